// Round 6
// baseline (2695.451 us; speedup 1.0000x reference)
//
#include <hip/hip_runtime.h>
#include <math.h>

// Problem constants
#define NN    8
#define CC_   96
#define HH    56
#define WW    56
#define HWHW  (HH*WW)            // 3136
#define NPIX  (NN*HWHW)          // 25088
#define NELEM (NN*CC_*HWHW)      // 2408448
#define GROUPS 4
#define IG    24                 // channels per group
#define KTAP  216                // 24*9
#define NITER 25
#define EPSV  1e-12f

// Weight pack: per (chunk = g*4+ocg, ic): 3 ky-blocks of 24 floats (18 used:
// [kx*6 + o]). Keeps live weight regs at ~24 in the inner loop.
#define WCH   72
#define WTOT  (16*IG*WCH)        // 27648

// bf16 helpers (RNE pack, cheap unpack) — used by the MLP only
__device__ __forceinline__ unsigned bf2pack(float a, float b) {
    unsigned ua = __float_as_uint(a), ub = __float_as_uint(b);
    ua += 0x7fffu + ((ua >> 16) & 1u);
    ub += 0x7fffu + ((ub >> 16) & 1u);
    return (ua >> 16) | (ub & 0xffff0000u);
}
__device__ __forceinline__ unsigned short bf1pack(float a) {
    unsigned ua = __float_as_uint(a);
    ua += 0x7fffu + ((ua >> 16) & 1u);
    return (unsigned short)(ua >> 16);
}
__device__ __forceinline__ float bflo(unsigned u) { return __uint_as_float(u << 16); }
__device__ __forceinline__ float bfhi(unsigned u) { return __uint_as_float(u & 0xffff0000u); }
__device__ __forceinline__ float bfs(unsigned short u) { return __uint_as_float(((unsigned)u) << 16); }

// ---------------------------------------------------------------------------
// Normalize weights; pack forward (Wf) and flipped-transposed (Wt) layouts.
__global__ void wnorm3_kernel(const float* __restrict__ w_in,
                              float* __restrict__ Wf, float* __restrict__ Wt) {
    int o = blockIdx.x;          // 96
    int t = threadIdx.x;         // 256
    float myv = (t < KTAP) ? fabsf(w_in[o*KTAP + t]) : 0.f;
    float v = myv;
    #pragma unroll
    for (int off = 32; off; off >>= 1) v += __shfl_down(v, off, 64);
    __shared__ float red[4];
    if ((t & 63) == 0) red[t >> 6] = v;
    __syncthreads();
    float s = red[0] + red[1] + red[2] + red[3];
    if (t < KTAP) {
        float w = myv / (s + EPSV);
        int ic = t / 9, k = t % 9;
        int ky = k / 3, kx = k % 3;
        int g  = o / IG, ol = o % IG;
        Wf[((g*4 + ol/6)*IG + ic)*WCH + ky*24 + kx*6 + (ol%6)] = w;
        int kf = 8 - k; int kyf = kf / 3, kxf = kf % 3;
        Wt[((g*4 + ic/6)*IG + ol)*WCH + kyf*24 + kxf*6 + (ic%6)] = w;
    }
}

// ---------------------------------------------------------------------------
// LN (channels-first, eps 1e-6) -> relu -> x / (sum_c x + EPS)  => X
__global__ void ln1_kernel(const float* __restrict__ x, const float* __restrict__ lw,
                           const float* __restrict__ lb, float* __restrict__ X) {
    int p = blockIdx.x * blockDim.x + threadIdx.x;
    if (p >= NPIX) return;
    int n = p / HWHW, hw = p % HWHW;
    const float* xp = x + (size_t)n*CC_*HWHW + hw;
    float s = 0.f, ss = 0.f;
    for (int c = 0; c < CC_; ++c) { float v = xp[(size_t)c*HWHW]; s += v; ss += v*v; }
    float u  = s * (1.f/CC_);
    float var = ss * (1.f/CC_) - u*u;
    float rs = rsqrtf(var + 1e-6f);
    float sr = 0.f;
    for (int c = 0; c < CC_; ++c) {
        float v = xp[(size_t)c*HWHW];
        float a = fmaxf((v-u)*rs*lw[c] + lb[c], 0.f);
        sr += a;
    }
    float inv = 1.f / (sr + EPSV);
    float* Xp = X + (size_t)n*CC_*HWHW + hw;
    for (int c = 0; c < CC_; ++c) {
        float v = xp[(size_t)c*HWHW];
        float a = fmaxf((v-u)*rs*lw[c] + lb[c], 0.f);
        Xp[(size_t)c*HWHW] = a * inv;
    }
}

// ---------------------------------------------------------------------------
__global__ void fill_kernel(float* __restrict__ p, int n, float v) {
    int i = blockIdx.x * blockDim.x + threadIdx.x;
    if (i < n) p[i] = v;
}

// ---------------------------------------------------------------------------
// One fused NNMF iteration. Block = (n, g, 4-row band). 512 thr = 8 waves.
// Phase 0: stage HuN = HuI/Stot over 8-row tile into LDS.
// Phase 1: convT on 6-row R band (halo recompute); R = X/(recon+EPS) in regs.
// Phase 1s: write R into LDS (aliases HuN region after barrier).
// Phase 2: forward conv on 4-row band; h = HuN*acc; write HuO; per-group
//          channel-sums reduced in LDS, plain-stored to Snxt (no atomics).
// S buffers are [4 groups][NPIX]; Hu and S ping-pong across iterations so no
// intra-dispatch read/write races exist.
__global__ __launch_bounds__(512, 4) void nnmf_iter_kernel(
        const float* __restrict__ HuI, float* __restrict__ HuO,
        const float* __restrict__ Wt, const float* __restrict__ Wf,
        const float* __restrict__ X,
        const float* __restrict__ Scur, float* __restrict__ Snxt) {
    __shared__ float smem[IG*8*60];      // 46.1 KB: HuN tile, then R tile [24][6][60]
    __shared__ float sinv[8*58];         // per-pixel 1/(S+eps) for the tile
    __shared__ float sacc[4*224];        // per-ocg channel-sum partials
    int b   = blockIdx.x;                // 8*4*14 = 448
    int rt  = b % 14;
    int g   = (b / 14) % GROUPS;
    int n   = b / 56;
    int tid = threadIdx.x;
    int r0  = rt*4;

    // ---- 0a: per-pixel inverse channel-sum, tile rows r0-2..r0+5, cols -1..56
    if (tid < 464) {
        int r = tid / 58, pos = tid % 58;
        int gr = r0 - 2 + r, gc = pos - 1;
        float stot = 1.f;
        if (gr >= 0 && gr < HH && gc >= 0 && gc < WW) {
            int p = n*HWHW + gr*WW + gc;
            stot = Scur[p] + Scur[NPIX + p] + Scur[2*NPIX + p] + Scur[3*NPIX + p];
        }
        sinv[tid] = 1.f / (stot + EPSV);
    }
    __syncthreads();

    // ---- 0b: stage HuN
    const float* hub = HuI + ((size_t)n*CC_ + g*IG) * HWHW;
    for (int idx = tid; idx < IG*8*58; idx += 512) {
        int ic  = idx / 464;
        int rem = idx % 464;
        int r   = rem / 58, pos = rem % 58;
        int gr = r0 - 2 + r, gc = pos - 1;
        float v = 0.f;
        if (gr >= 0 && gr < HH && gc >= 0 && gc < WW)
            v = hub[(size_t)ic*HWHW + gr*WW + gc] * sinv[r*58 + pos];
        smem[ic*480 + r*60 + pos] = v;
    }
    __syncthreads();

    // ---- phase 1: convT over 6-row R band; 8 waves = 4 ocg x 2 row-halves
    int wv   = tid >> 6;
    int lane = tid & 63;
    int ocg  = wv & 3;
    int rh   = wv >> 2;
    bool act1 = (lane < 42);
    int row = 0, x0 = 0;
    float acc[6][4] = {};
    if (act1) {
        int item = rh*42 + lane;       // 0..83 = 6 rows x 14 x4-tiles
        row = item / 14;               // R-band row 0..5 (global r0-1+row)
        x0  = (item % 14) * 4;
        int gr = r0 - 1 + row;
        if (gr >= 0 && gr < HH) {
            const float* Wc = Wt + (size_t)((g*4 + ocg)*IG) * WCH;
            #pragma unroll 1
            for (int hc = 0; hc < IG; ++hc) {
                const float* lb = &smem[hc*480 + row*60 + x0];
                const float* wp = Wc + hc*WCH;
                #pragma unroll
                for (int ky = 0; ky < 3; ++ky) {
                    float4 a  = *(const float4*)(lb + ky*60);
                    float2 c2 = *(const float2*)(lb + ky*60 + 4);
                    float v[6] = {a.x, a.y, a.z, a.w, c2.x, c2.y};
                    union { float4 q[5]; float f[20]; } wu;
                    const float4* wq = (const float4*)(wp + ky*24);
                    #pragma unroll
                    for (int j = 0; j < 5; ++j) wu.q[j] = wq[j];
                    #pragma unroll
                    for (int kx = 0; kx < 3; ++kx)
                        #pragma unroll
                        for (int o = 0; o < 6; ++o) {
                            float wvv = wu.f[kx*6 + o];
                            #pragma unroll
                            for (int p = 0; p < 4; ++p)
                                acc[o][p] = fmaf(v[kx+p], wvv, acc[o][p]);
                        }
                }
            }
            const float* Xb = X + ((size_t)n*CC_ + g*IG + ocg*6)*HWHW + gr*WW + x0;
            #pragma unroll
            for (int o = 0; o < 6; ++o) {
                float4 xx = *(const float4*)(Xb + (size_t)o*HWHW);
                acc[o][0] = xx.x / (acc[o][0] + EPSV);
                acc[o][1] = xx.y / (acc[o][1] + EPSV);
                acc[o][2] = xx.z / (acc[o][2] + EPSV);
                acc[o][3] = xx.w / (acc[o][3] + EPSV);
            }
        }
        // invalid rows keep acc == 0 -> R = 0 (conv zero-pad)
    }
    __syncthreads();   // all HuN reads complete; safe to overwrite with R

    // ---- 1s: store R tile [ch][6][60], cols at pos col+1
    if (act1) {
        #pragma unroll
        for (int o = 0; o < 6; ++o) {
            float* dst = &smem[(ocg*6 + o)*360 + row*60 + x0 + 1];
            dst[0] = acc[o][0]; dst[1] = acc[o][1];
            dst[2] = acc[o][2]; dst[3] = acc[o][3];
        }
    }
    if (tid < 288) {   // zero halo cols (pos 0 and 57)
        int ch = tid / 12, rem = tid % 12;
        int rr = rem >> 1, side = rem & 1;
        smem[ch*360 + rr*60 + (side ? 57 : 0)] = 0.f;
    }
    __syncthreads();

    // ---- phase 2: forward conv on 4-row band; 8 waves = 4 ocg x 2 row-pairs
    if (lane < 56) {
        int rp   = wv >> 2;
        int xt   = lane % 28;
        int rowh = lane / 28;
        int br   = rp*2 + rowh;          // band row 0..3
        int x2   = xt*2;
        int grow = r0 + br;
        const float* Wc = Wf + (size_t)((g*4 + ocg)*IG) * WCH;
        float a2[6][2] = {};
        #pragma unroll 1
        for (int ic = 0; ic < IG; ++ic) {
            const float* lb = &smem[ic*360 + br*60 + x2];
            const float* wp = Wc + ic*WCH;
            #pragma unroll
            for (int ky = 0; ky < 3; ++ky) {
                float2 aa = *(const float2*)(lb + ky*60);
                float2 bb = *(const float2*)(lb + ky*60 + 2);
                float v[4] = {aa.x, aa.y, bb.x, bb.y};
                union { float4 q[5]; float f[20]; } wu;
                const float4* wq = (const float4*)(wp + ky*24);
                #pragma unroll
                for (int j = 0; j < 5; ++j) wu.q[j] = wq[j];
                #pragma unroll
                for (int kx = 0; kx < 3; ++kx)
                    #pragma unroll
                    for (int o = 0; o < 6; ++o) {
                        float wvv = wu.f[kx*6 + o];
                        a2[o][0] = fmaf(v[kx+0], wvv, a2[o][0]);
                        a2[o][1] = fmaf(v[kx+1], wvv, a2[o][1]);
                    }
            }
        }
        // multiplicative update epilogue
        float i0 = sinv[(br+2)*58 + x2 + 1];
        float i1 = sinv[(br+2)*58 + x2 + 2];
        size_t hb = ((size_t)n*CC_ + g*IG + ocg*6)*HWHW + grow*WW + x2;
        float ps0 = 0.f, ps1 = 0.f;
        #pragma unroll
        for (int o = 0; o < 6; ++o) {
            float2 hu = *(const float2*)(HuI + hb + (size_t)o*HWHW);
            float h0 = hu.x * i0 * a2[o][0];
            float h1 = hu.y * i1 * a2[o][1];
            float2 hv = {h0, h1};
            *(float2*)(HuO + hb + (size_t)o*HWHW) = hv;
            ps0 += h0; ps1 += h1;
        }
        sacc[ocg*224 + br*56 + x2]     = ps0;
        sacc[ocg*224 + br*56 + x2 + 1] = ps1;
    }
    __syncthreads();

    // ---- reduce channel-sum partials across the 4 ocg waves; plain store
    if (tid < 224) {
        float s = sacc[tid] + sacc[224+tid] + sacc[448+tid] + sacc[672+tid];
        Snxt[(size_t)g*NPIX + n*HWHW + r0*WW + tid] = s;
    }
}

// ---------------------------------------------------------------------------
// x2 = x + Hu/(S4sum+EPS) -> d_out ; XLN = LN(x2) (over C, eps 1e-5)
__global__ void resln3_kernel(const float* __restrict__ x, const float* __restrict__ Hu,
                              const float* __restrict__ S4,
                              const float* __restrict__ lw, const float* __restrict__ lb,
                              float* __restrict__ out, float* __restrict__ XLN) {
    int p = blockIdx.x * blockDim.x + threadIdx.x;
    if (p >= NPIX) return;
    int n = p / HWHW, hw = p % HWHW;
    size_t base = (size_t)n*CC_*HWHW + hw;
    float stot = S4[p] + S4[NPIX+p] + S4[2*NPIX+p] + S4[3*NPIX+p];
    float sinv = 1.f / (stot + EPSV);
    float s = 0.f, ss = 0.f;
    for (int c = 0; c < CC_; ++c) {
        float v = x[base + (size_t)c*HWHW] + Hu[base + (size_t)c*HWHW] * sinv;
        out[base + (size_t)c*HWHW] = v;
        s += v; ss += v*v;
    }
    float u  = s * (1.f/CC_);
    float var = ss * (1.f/CC_) - u*u;
    float rs = rsqrtf(var + 1e-5f);
    for (int c = 0; c < CC_; ++c) {
        float v = out[base + (size_t)c*HWHW];
        XLN[base + (size_t)c*HWHW] = (v-u)*rs*lw[c] + lb[c];
    }
}

// ---------------------------------------------------------------------------
// Fused MLP (round-5 version, measured ~100 us): bf16 LDS staging.
__global__ __launch_bounds__(384) void mlp4_kernel(const float* __restrict__ XLN,
                                                   const float* __restrict__ w1,
                                                   const float* __restrict__ b1,
                                                   const float* __restrict__ w2,
                                                   const float* __restrict__ b2,
                                                   float* __restrict__ out) {
    __shared__ unsigned short lx[CC_*32];      // 6144 B
    __shared__ unsigned short lh[384*32];      // 24576 B (reused for partials)
    int blk = blockIdx.x;                // 784
    int tid = threadIdx.x;               // 384
    int p0  = blk * 32;
    int n   = p0 / HWHW;
    int hw0 = p0 % HWHW;
    const float* Xb = XLN + (size_t)n*CC_*HWHW + hw0;
    for (int idx = tid; idx < CC_*32; idx += 384) {
        int c = idx >> 5, t = idx & 31;
        lx[c*32 + t] = bf1pack(Xb[(size_t)c*HWHW + t]);
    }
    __syncthreads();

    // ---- GEMM1: [32 x 96] @ [96 x 384]
    {
        int tg = tid / 48, jg = tid % 48;
        int t0 = tg*4, j0 = jg*8;
        float acc1[4][8] = {};
        for (int k = 0; k < CC_; ++k) {
            uint2 a2 = *(const uint2*)&lx[k*32 + t0];
            float av[4] = {bflo(a2.x), bfhi(a2.x), bflo(a2.y), bfhi(a2.y)};
            float4 wA = *(const float4*)&w1[(size_t)k*384 + j0];
            float4 wB = *(const float4*)&w1[(size_t)k*384 + j0 + 4];
            float wv[8] = {wA.x,wA.y,wA.z,wA.w,wB.x,wB.y,wB.z,wB.w};
            #pragma unroll
            for (int i = 0; i < 4; ++i)
                #pragma unroll
                for (int j = 0; j < 8; ++j)
                    acc1[i][j] = fmaf(av[i], wv[j], acc1[i][j]);
        }
        float4 bA = *(const float4*)&b1[j0];
        float4 bB = *(const float4*)&b1[j0+4];
        float bv[8] = {bA.x,bA.y,bA.z,bA.w,bB.x,bB.y,bB.z,bB.w};
        int swz = jg & 7;
        #pragma unroll
        for (int jj = 0; jj < 8; ++jj) {
            float h0,h1,h2,h3,h;
            h = acc1[0][jj] + bv[jj]; h0 = 0.5f*h*(1.f+erff(h*0.70710678f));
            h = acc1[1][jj] + bv[jj]; h1 = 0.5f*h*(1.f+erff(h*0.70710678f));
            h = acc1[2][jj] + bv[jj]; h2 = 0.5f*h*(1.f+erff(h*0.70710678f));
            h = acc1[3][jj] + bv[jj]; h3 = 0.5f*h*(1.f+erff(h*0.70710678f));
            int chunk = (t0 >> 2) ^ swz;
            uint2 pk = {bf2pack(h0,h1), bf2pack(h2,h3)};
            *(uint2*)&lh[(j0+jj)*32 + chunk*4] = pk;
        }
    }
    __syncthreads();

    // ---- GEMM2: [32 x 384] @ [384 x 96], k split 4 ways
    int kq = tid / 96;
    int r  = tid % 96;
    int cg = r / 8, tg2 = r % 8;
    int c0 = cg*8, t0b = tg2*4;
    float acc2[4][8] = {};
    for (int kk = 0; kk < 96; ++kk) {
        int k = kq*96 + kk;
        int chunk = (t0b >> 2) ^ ((k >> 3) & 7);
        uint2 h2 = *(const uint2*)&lh[k*32 + chunk*4];
        float av[4] = {bflo(h2.x), bfhi(h2.x), bflo(h2.y), bfhi(h2.y)};
        float4 wA = *(const float4*)&w2[(size_t)k*CC_ + c0];
        float4 wB = *(const float4*)&w2[(size_t)k*CC_ + c0 + 4];
        float wv[8] = {wA.x,wA.y,wA.z,wA.w,wB.x,wB.y,wB.z,wB.w};
        #pragma unroll
        for (int i = 0; i < 4; ++i)
            #pragma unroll
            for (int cc = 0; cc < 8; ++cc)
                acc2[i][cc] = fmaf(av[i], wv[cc], acc2[i][cc]);
    }
    __syncthreads();   // all reads of lh done; reuse as bf16 partials [kq][t][c]
    #pragma unroll
    for (int i = 0; i < 4; ++i) {
        uint4 pw;
        pw.x = bf2pack(acc2[i][0], acc2[i][1]);
        pw.y = bf2pack(acc2[i][2], acc2[i][3]);
        pw.z = bf2pack(acc2[i][4], acc2[i][5]);
        pw.w = bf2pack(acc2[i][6], acc2[i][7]);
        *(uint4*)&lh[(kq*32 + t0b + i)*CC_ + c0] = pw;
    }
    __syncthreads();

    // ---- reduce 4 partials + bias, accumulate into out
    {
        int c  = tid % CC_;
        int tq = tid / CC_;
        float bc = b2[c];
        size_t obase = ((size_t)n*CC_ + c)*HWHW + hw0 + tq*8;
        float4 o0 = *(const float4*)(out + obase);
        float4 o1 = *(const float4*)(out + obase + 4);
        float vsum[8];
        #pragma unroll
        for (int tt = 0; tt < 8; ++tt) {
            int t = tq*8 + tt;
            vsum[tt] = bfs(lh[(0*32+t)*CC_+c]) + bfs(lh[(1*32+t)*CC_+c])
                     + bfs(lh[(2*32+t)*CC_+c]) + bfs(lh[(3*32+t)*CC_+c]) + bc;
        }
        o0.x += vsum[0]; o0.y += vsum[1]; o0.z += vsum[2]; o0.w += vsum[3];
        o1.x += vsum[4]; o1.y += vsum[5]; o1.z += vsum[6]; o1.w += vsum[7];
        *(float4*)(out + obase)     = o0;
        *(float4*)(out + obase + 4) = o1;
    }
}

// ---------------------------------------------------------------------------
extern "C" void kernel_launch(void* const* d_in, const int* in_sizes, int n_in,
                              void* d_out, int out_size, void* d_ws, size_t ws_size,
                              hipStream_t stream) {
    const float* x    = (const float*)d_in[0];
    const float* ln1w = (const float*)d_in[1];
    const float* ln1b = (const float*)d_in[2];
    const float* wnn  = (const float*)d_in[3];
    const float* ln2w = (const float*)d_in[4];
    const float* ln2b = (const float*)d_in[5];
    const float* w1   = (const float*)d_in[6];
    const float* b1   = (const float*)d_in[7];
    const float* w2   = (const float*)d_in[8];
    const float* b2   = (const float*)d_in[9];
    float* out = (float*)d_out;
    float* ws  = (float*)d_ws;

    float* Wf  = ws;                      // 27648
    float* Wt  = Wf + WTOT;               // 27648
    float* X   = Wt + WTOT;               // NELEM (reused as XLN at the end)
    float* Hu0 = X  + NELEM;              // NELEM
    float* Hu1 = Hu0 + NELEM;             // NELEM
    float* SA  = Hu1 + NELEM;             // 4*NPIX (per-group channel sums)
    float* SB  = SA + 4*NPIX;             // 4*NPIX

    wnorm3_kernel<<<CC_, 256, 0, stream>>>(wnn, Wf, Wt);
    ln1_kernel<<<NPIX/256, 256, 0, stream>>>(x, ln1w, ln1b, X);
    fill_kernel<<<NELEM/256, 256, 0, stream>>>(Hu0, NELEM, 1.f/CC_);
    fill_kernel<<<(4*NPIX)/256, 256, 0, stream>>>(SA, 4*NPIX, 0.25f);

    for (int it = 0; it < NITER; ++it) {
        const float* HuI = (it & 1) ? Hu1 : Hu0;
        float*       HuO = (it & 1) ? Hu0 : Hu1;
        const float* Scur = (it & 1) ? SB : SA;
        float*       Snxt = (it & 1) ? SA : SB;
        nnmf_iter_kernel<<<448, 512, 0, stream>>>(HuI, HuO, Wt, Wf, X, Scur, Snxt);
    }
    // 25 iters: final Hu in Hu1, final S in SB (it=24 even)

    resln3_kernel<<<NPIX/256, 256, 0, stream>>>(x, Hu1, SB, ln2w, ln2b, out, X);
    mlp4_kernel<<<NPIX/32, 384, 0, stream>>>(X, w1, b1, w2, b2, out);
}

// Round 7
// 778.144 us; speedup vs baseline: 3.4640x; 3.4640x over previous
//
#include <hip/hip_runtime.h>
#include <math.h>

typedef unsigned short ushort_t;
typedef __attribute__((ext_vector_type(8))) short bhalf8;
typedef __attribute__((ext_vector_type(4))) float floatx4;

// Problem constants
#define NN    8
#define CC_   96
#define HH    56
#define WW    56
#define HWHW  (HH*WW)            // 3136
#define NPIX  (NN*HWHW)          // 25088
#define NELEM (NN*CC_*HWHW)      // 2408448
#define GROUPS 4
#define IG    24                 // channels per group
#define NITER 25
#define EPSV  1e-12f
#define TS    40                 // LDS ic-slot stride (ushorts): 80 B -> b128-aligned, low conflict

// bf16 helpers (RNE)
__device__ __forceinline__ unsigned bf2pack(float a, float b) {
    unsigned ua = __float_as_uint(a), ub = __float_as_uint(b);
    ua += 0x7fffu + ((ua >> 16) & 1u);
    ub += 0x7fffu + ((ub >> 16) & 1u);
    return (ua >> 16) | (ub & 0xffff0000u);
}
__device__ __forceinline__ ushort_t bf1pack(float a) {
    unsigned ua = __float_as_uint(a);
    ua += 0x7fffu + ((ua >> 16) & 1u);
    return (ushort_t)(ua >> 16);
}
__device__ __forceinline__ float bflo(unsigned u) { return __uint_as_float(u << 16); }
__device__ __forceinline__ float bfhi(unsigned u) { return __uint_as_float(u & 0xffff0000u); }
__device__ __forceinline__ float bfs(ushort_t u) { return __uint_as_float(((unsigned)u) << 16); }

// ---------------------------------------------------------------------------
// Normalize weights -> Wn[96][216] fp32  (Wn[o][ic*9 + k])
__global__ void wnorm_n_kernel(const float* __restrict__ w_in, float* __restrict__ Wn) {
    int o = blockIdx.x;          // 96
    int t = threadIdx.x;         // 256
    float myv = (t < 216) ? fabsf(w_in[o*216 + t]) : 0.f;
    float v = myv;
    #pragma unroll
    for (int off = 32; off; off >>= 1) v += __shfl_down(v, off, 64);
    __shared__ float red[4];
    if ((t & 63) == 0) red[t >> 6] = v;
    __syncthreads();
    float s = red[0] + red[1] + red[2] + red[3];
    if (t < 216) Wn[o*216 + t] = myv / (s + EPSV);
}

// ---------------------------------------------------------------------------
// Pack A-fragments (bf16) for MFMA 16x16x32.
// Layout: P[((gt*2)+ot)*64 + lane]*8  where gt = g*9 + tap.
// A[m = ot*16 + (lane&15)][k = tap*32 + (quad*8+j)]
// sel 0 (Wf, forward):  val = Wn[(g*24+m)*216 + kc*9 + tap]
// sel 1 (Wt, transposed): val = Wn[(g*24+kc)*216 + m*9 + (8-tap)]
__global__ void wpack_kernel(const float* __restrict__ Wn,
                             ushort_t* __restrict__ WfP, ushort_t* __restrict__ WtP) {
    int bi = blockIdx.x;             // 144 = 2 sel * 72
    int sel = bi / 72;
    int rem = bi % 72;
    int ot = rem & 1;
    int gt = rem >> 1;               // g*9 + tap
    int g = gt / 9, tap = gt % 9;
    int lane = threadIdx.x;          // 64
    int quad = lane >> 4, nn = lane & 15;
    int m = ot*16 + nn;
    ushort_t v[8];
    #pragma unroll
    for (int j = 0; j < 8; ++j) {
        int kc = quad*8 + j;
        float val = 0.f;
        if (m < IG && kc < IG) {
            if (sel == 0) val = Wn[(g*IG + m)*216 + kc*9 + tap];
            else          val = Wn[(g*IG + kc)*216 + m*9 + (8 - tap)];
        }
        v[j] = bf1pack(val);
    }
    ushort_t* dst = (sel ? WtP : WfP) + ((size_t)(gt*2 + ot)*64 + lane)*8;
    *(uint4*)dst = *(uint4*)v;
}

// ---------------------------------------------------------------------------
// LN (channels-first, eps 1e-6) -> relu -> x / (sum_c x + EPS)  => X
__global__ void ln1_kernel(const float* __restrict__ x, const float* __restrict__ lw,
                           const float* __restrict__ lb, float* __restrict__ X) {
    int p = blockIdx.x * blockDim.x + threadIdx.x;
    if (p >= NPIX) return;
    int n = p / HWHW, hw = p % HWHW;
    const float* xp = x + (size_t)n*CC_*HWHW + hw;
    float s = 0.f, ss = 0.f;
    for (int c = 0; c < CC_; ++c) { float v = xp[(size_t)c*HWHW]; s += v; ss += v*v; }
    float u  = s * (1.f/CC_);
    float var = ss * (1.f/CC_) - u*u;
    float rs = rsqrtf(var + 1e-6f);
    float sr = 0.f;
    for (int c = 0; c < CC_; ++c) {
        float v = xp[(size_t)c*HWHW];
        float a = fmaxf((v-u)*rs*lw[c] + lb[c], 0.f);
        sr += a;
    }
    float inv = 1.f / (sr + EPSV);
    float* Xp = X + (size_t)n*CC_*HWHW + hw;
    for (int c = 0; c < CC_; ++c) {
        float v = xp[(size_t)c*HWHW];
        float a = fmaxf((v-u)*rs*lw[c] + lb[c], 0.f);
        Xp[(size_t)c*HWHW] = a * inv;
    }
}

// ---------------------------------------------------------------------------
__global__ void fill_kernel(float* __restrict__ p, int n, float v) {
    int i = blockIdx.x * blockDim.x + threadIdx.x;
    if (i < n) p[i] = v;
}

// ---------------------------------------------------------------------------
// Kernel A: R = X / (convT(Hu/S) + EPS), R stored bf16 planar.
// Block = (n, g, 4-row band); 512 thr = 8 waves = 4 rows x 2 oc-tiles.
// LDS tile: HuN bf16 [6 rows][58 pos][TS ic-slots] (ic 24..31 zeroed).
__global__ __launch_bounds__(512) void ratio_mfma_kernel(
        const float* __restrict__ HuI, const float* __restrict__ Scur,
        const ushort_t* __restrict__ WtP, const float* __restrict__ X,
        ushort_t* __restrict__ Rg) {
    __shared__ ushort_t tile[6*58*TS];   // 27840 B
    __shared__ float sinv[6*58];
    int b   = blockIdx.x;                // 448
    int rt  = b % 14;
    int g   = (b / 14) & 3;
    int n   = b / 56;
    int tid = threadIdx.x;
    int r0  = rt*4;

    if (tid < 348) {
        int r = tid / 58, pos = tid % 58;
        int gr = r0 - 1 + r, gc = pos - 1;
        float st = 1.f;
        if (gr >= 0 && gr < HH && gc >= 0 && gc < WW) {
            int p = n*HWHW + gr*WW + gc;
            st = Scur[p] + Scur[NPIX+p] + Scur[2*NPIX+p] + Scur[3*NPIX+p];
        }
        sinv[tid] = 1.f / (st + EPSV);
    }
    __syncthreads();

    // stage HuN = Hu * sinv as bf16 pairs; pr 12..15 -> zero pad (ic 24..31)
    const float* hub = HuI + ((size_t)n*CC_ + g*IG) * HWHW;
    for (int idx = tid; idx < 16*348; idx += 512) {
        int pr  = idx / 348;
        int rem = idx % 348;
        int r = rem / 58, pos = rem % 58;
        int gr = r0 - 1 + r, gc = pos - 1;
        unsigned pk = 0;
        if (pr < 12 && gr >= 0 && gr < HH && gc >= 0 && gc < WW) {
            float si = sinv[rem];
            const float* hp = hub + (size_t)(2*pr)*HWHW + gr*WW + gc;
            pk = bf2pack(hp[0]*si, hp[HWHW]*si);
        }
        *(unsigned*)&tile[rem*TS + 2*pr] = pk;
    }
    __syncthreads();

    int waveId = tid >> 6, lane = tid & 63;
    int w  = waveId & 3;                 // row within band
    int ot = waveId >> 2;                // oc-tile 0/1
    int quad = lane >> 4, nn = lane & 15;

    // preload the 9 A-fragments (coalesced global, bf16)
    const ushort_t* ap = WtP + ((size_t)(g*9*2 + ot)*64 + lane)*8;
    bhalf8 afr[9];
    #pragma unroll
    for (int t = 0; t < 9; ++t) afr[t] = *(const bhalf8*)(ap + (size_t)t*2*64*8);

    floatx4 acc[4];
    #pragma unroll
    for (int pt = 0; pt < 4; ++pt) acc[pt] = (floatx4){0.f,0.f,0.f,0.f};
    const int x0s[4] = {0, 16, 32, 40};

    #pragma unroll
    for (int t = 0; t < 9; ++t) {
        int ky = t / 3, kx = t % 3;
        int rbase = (w + ky)*58 + kx + nn;
        #pragma unroll
        for (int pt = 0; pt < 4; ++pt) {
            bhalf8 bfr = *(const bhalf8*)&tile[(rbase + x0s[pt])*TS + quad*8];
            acc[pt] = __builtin_amdgcn_mfma_f32_16x16x32_bf16(afr[t], bfr, acc[pt], 0, 0, 0);
        }
    }

    // epilogue: R = X/(acc+eps), bf16 store (overlap px 40..47 double-written identically)
    int grow = r0 + w;
    int mb = ot*16 + quad*4;
    if (mb < IG) {
        #pragma unroll
        for (int pt = 0; pt < 4; ++pt) {
            int px = x0s[pt] + nn;
            size_t base = ((size_t)n*CC_ + g*IG + mb)*HWHW + grow*WW + px;
            #pragma unroll
            for (int r = 0; r < 4; ++r) {
                float xv = X[base + (size_t)r*HWHW];
                Rg[base + (size_t)r*HWHW] = bf1pack(xv / (acc[pt][r] + EPSV));
            }
        }
    }
}

// ---------------------------------------------------------------------------
// Kernel B: h = (Hu/S) * conv(R); HuO = h; Snxt[g] = per-pixel sum_c h.
__global__ __launch_bounds__(512) void update_mfma_kernel(
        const ushort_t* __restrict__ Rg, const float* __restrict__ HuI,
        float* __restrict__ HuO, const float* __restrict__ Scur,
        float* __restrict__ Snxt, const ushort_t* __restrict__ WfP) {
    __shared__ ushort_t tile[6*58*TS];   // 27840 B
    __shared__ float sinv2[224];
    __shared__ float sacc[2*224];
    int b   = blockIdx.x;
    int rt  = b % 14;
    int g   = (b / 14) & 3;
    int n   = b / 56;
    int tid = threadIdx.x;
    int r0  = rt*4;

    if (tid < 224) {
        int p = n*HWHW + (r0 + tid/56)*WW + (tid % 56);
        float st = Scur[p] + Scur[NPIX+p] + Scur[2*NPIX+p] + Scur[3*NPIX+p];
        sinv2[tid] = 1.f / (st + EPSV);
    }

    // stage R tile (already bf16)
    const ushort_t* rb = Rg + ((size_t)n*CC_ + g*IG) * HWHW;
    for (int idx = tid; idx < 16*348; idx += 512) {
        int pr  = idx / 348;
        int rem = idx % 348;
        int r = rem / 58, pos = rem % 58;
        int gr = r0 - 1 + r, gc = pos - 1;
        unsigned pk = 0;
        if (pr < 12 && gr >= 0 && gr < HH && gc >= 0 && gc < WW) {
            const ushort_t* rp = rb + (size_t)(2*pr)*HWHW + gr*WW + gc;
            pk = (unsigned)rp[0] | ((unsigned)rp[HWHW] << 16);
        }
        *(unsigned*)&tile[rem*TS + 2*pr] = pk;
    }
    __syncthreads();

    int waveId = tid >> 6, lane = tid & 63;
    int w  = waveId & 3;
    int ot = waveId >> 2;
    int quad = lane >> 4, nn = lane & 15;

    const ushort_t* ap = WfP + ((size_t)(g*9*2 + ot)*64 + lane)*8;
    bhalf8 afr[9];
    #pragma unroll
    for (int t = 0; t < 9; ++t) afr[t] = *(const bhalf8*)(ap + (size_t)t*2*64*8);

    floatx4 acc[4];
    #pragma unroll
    for (int pt = 0; pt < 4; ++pt) acc[pt] = (floatx4){0.f,0.f,0.f,0.f};
    const int x0s[4] = {0, 16, 32, 40};

    #pragma unroll
    for (int t = 0; t < 9; ++t) {
        int ky = t / 3, kx = t % 3;
        int rbase = (w + ky)*58 + kx + nn;
        #pragma unroll
        for (int pt = 0; pt < 4; ++pt) {
            bhalf8 bfr = *(const bhalf8*)&tile[(rbase + x0s[pt])*TS + quad*8];
            acc[pt] = __builtin_amdgcn_mfma_f32_16x16x32_bf16(afr[t], bfr, acc[pt], 0, 0, 0);
        }
    }

    // epilogue: multiplicative update + channel-sum reduction
    int grow = r0 + w;
    int mb = ot*16 + quad*4;
    #pragma unroll
    for (int pt = 0; pt < 4; ++pt) {
        int px = x0s[pt] + nn;
        float psum = 0.f;
        if (mb < IG) {
            float si = sinv2[w*56 + px];
            size_t base = ((size_t)n*CC_ + g*IG + mb)*HWHW + grow*WW + px;
            #pragma unroll
            for (int r = 0; r < 4; ++r) {
                float h = HuI[base + (size_t)r*HWHW] * si * acc[pt][r];
                HuO[base + (size_t)r*HWHW] = h;
                psum += h;
            }
        }
        psum += __shfl_down(psum, 32, 64);
        psum += __shfl_down(psum, 16, 64);
        if (lane < 16) sacc[ot*224 + w*56 + px] = psum;   // overlaps write same value
    }
    __syncthreads();
    if (tid < 224) {
        Snxt[(size_t)g*NPIX + n*HWHW + (r0 + tid/56)*WW + (tid % 56)]
            = sacc[tid] + sacc[224 + tid];
    }
}

// ---------------------------------------------------------------------------
// x2 = x + Hu/(S4sum+EPS) -> d_out ; XLN = LN(x2) (over C, eps 1e-5)
__global__ void resln3_kernel(const float* __restrict__ x, const float* __restrict__ Hu,
                              const float* __restrict__ S4,
                              const float* __restrict__ lw, const float* __restrict__ lb,
                              float* __restrict__ out, float* __restrict__ XLN) {
    int p = blockIdx.x * blockDim.x + threadIdx.x;
    if (p >= NPIX) return;
    int n = p / HWHW, hw = p % HWHW;
    size_t base = (size_t)n*CC_*HWHW + hw;
    float stot = S4[p] + S4[NPIX+p] + S4[2*NPIX+p] + S4[3*NPIX+p];
    float sinv = 1.f / (stot + EPSV);
    float s = 0.f, ss = 0.f;
    for (int c = 0; c < CC_; ++c) {
        float v = x[base + (size_t)c*HWHW] + Hu[base + (size_t)c*HWHW] * sinv;
        out[base + (size_t)c*HWHW] = v;
        s += v; ss += v*v;
    }
    float u  = s * (1.f/CC_);
    float var = ss * (1.f/CC_) - u*u;
    float rs = rsqrtf(var + 1e-5f);
    for (int c = 0; c < CC_; ++c) {
        float v = out[base + (size_t)c*HWHW];
        XLN[base + (size_t)c*HWHW] = (v-u)*rs*lw[c] + lb[c];
    }
}

// ---------------------------------------------------------------------------
// Fused MLP (round-5 version, measured ~100 us): bf16 LDS staging.
__global__ __launch_bounds__(384) void mlp4_kernel(const float* __restrict__ XLN,
                                                   const float* __restrict__ w1,
                                                   const float* __restrict__ b1,
                                                   const float* __restrict__ w2,
                                                   const float* __restrict__ b2,
                                                   float* __restrict__ out) {
    __shared__ ushort_t lx[CC_*32];      // 6144 B
    __shared__ ushort_t lh[384*32];      // 24576 B (reused for partials)
    int blk = blockIdx.x;                // 784
    int tid = threadIdx.x;               // 384
    int p0  = blk * 32;
    int n   = p0 / HWHW;
    int hw0 = p0 % HWHW;
    const float* Xb = XLN + (size_t)n*CC_*HWHW + hw0;
    for (int idx = tid; idx < CC_*32; idx += 384) {
        int c = idx >> 5, t = idx & 31;
        lx[c*32 + t] = bf1pack(Xb[(size_t)c*HWHW + t]);
    }
    __syncthreads();

    {
        int tg = tid / 48, jg = tid % 48;
        int t0 = tg*4, j0 = jg*8;
        float acc1[4][8] = {};
        for (int k = 0; k < CC_; ++k) {
            uint2 a2 = *(const uint2*)&lx[k*32 + t0];
            float av[4] = {bflo(a2.x), bfhi(a2.x), bflo(a2.y), bfhi(a2.y)};
            float4 wA = *(const float4*)&w1[(size_t)k*384 + j0];
            float4 wB = *(const float4*)&w1[(size_t)k*384 + j0 + 4];
            float wv[8] = {wA.x,wA.y,wA.z,wA.w,wB.x,wB.y,wB.z,wB.w};
            #pragma unroll
            for (int i = 0; i < 4; ++i)
                #pragma unroll
                for (int j = 0; j < 8; ++j)
                    acc1[i][j] = fmaf(av[i], wv[j], acc1[i][j]);
        }
        float4 bA = *(const float4*)&b1[j0];
        float4 bB = *(const float4*)&b1[j0+4];
        float bv[8] = {bA.x,bA.y,bA.z,bA.w,bB.x,bB.y,bB.z,bB.w};
        int swz = jg & 7;
        #pragma unroll
        for (int jj = 0; jj < 8; ++jj) {
            float h0,h1,h2,h3,h;
            h = acc1[0][jj] + bv[jj]; h0 = 0.5f*h*(1.f+erff(h*0.70710678f));
            h = acc1[1][jj] + bv[jj]; h1 = 0.5f*h*(1.f+erff(h*0.70710678f));
            h = acc1[2][jj] + bv[jj]; h2 = 0.5f*h*(1.f+erff(h*0.70710678f));
            h = acc1[3][jj] + bv[jj]; h3 = 0.5f*h*(1.f+erff(h*0.70710678f));
            int chunk = (t0 >> 2) ^ swz;
            uint2 pk = {bf2pack(h0,h1), bf2pack(h2,h3)};
            *(uint2*)&lh[(j0+jj)*32 + chunk*4] = pk;
        }
    }
    __syncthreads();

    int kq = tid / 96;
    int r  = tid % 96;
    int cg = r / 8, tg2 = r % 8;
    int c0 = cg*8, t0b = tg2*4;
    float acc2[4][8] = {};
    for (int kk = 0; kk < 96; ++kk) {
        int k = kq*96 + kk;
        int chunk = (t0b >> 2) ^ ((k >> 3) & 7);
        uint2 h2 = *(const uint2*)&lh[k*32 + chunk*4];
        float av[4] = {bflo(h2.x), bfhi(h2.x), bflo(h2.y), bfhi(h2.y)};
        float4 wA = *(const float4*)&w2[(size_t)k*CC_ + c0];
        float4 wB = *(const float4*)&w2[(size_t)k*CC_ + c0 + 4];
        float wv[8] = {wA.x,wA.y,wA.z,wA.w,wB.x,wB.y,wB.z,wB.w};
        #pragma unroll
        for (int i = 0; i < 4; ++i)
            #pragma unroll
            for (int cc = 0; cc < 8; ++cc)
                acc2[i][cc] = fmaf(av[i], wv[cc], acc2[i][cc]);
    }
    __syncthreads();
    #pragma unroll
    for (int i = 0; i < 4; ++i) {
        uint4 pw;
        pw.x = bf2pack(acc2[i][0], acc2[i][1]);
        pw.y = bf2pack(acc2[i][2], acc2[i][3]);
        pw.z = bf2pack(acc2[i][4], acc2[i][5]);
        pw.w = bf2pack(acc2[i][6], acc2[i][7]);
        *(uint4*)&lh[(kq*32 + t0b + i)*CC_ + c0] = pw;
    }
    __syncthreads();

    {
        int c  = tid % CC_;
        int tq = tid / CC_;
        float bc = b2[c];
        size_t obase = ((size_t)n*CC_ + c)*HWHW + hw0 + tq*8;
        float4 o0 = *(const float4*)(out + obase);
        float4 o1 = *(const float4*)(out + obase + 4);
        float vsum[8];
        #pragma unroll
        for (int tt = 0; tt < 8; ++tt) {
            int t = tq*8 + tt;
            vsum[tt] = bfs(lh[(0*32+t)*CC_+c]) + bfs(lh[(1*32+t)*CC_+c])
                     + bfs(lh[(2*32+t)*CC_+c]) + bfs(lh[(3*32+t)*CC_+c]) + bc;
        }
        o0.x += vsum[0]; o0.y += vsum[1]; o0.z += vsum[2]; o0.w += vsum[3];
        o1.x += vsum[4]; o1.y += vsum[5]; o1.z += vsum[6]; o1.w += vsum[7];
        *(float4*)(out + obase)     = o0;
        *(float4*)(out + obase + 4) = o1;
    }
}

// ---------------------------------------------------------------------------
extern "C" void kernel_launch(void* const* d_in, const int* in_sizes, int n_in,
                              void* d_out, int out_size, void* d_ws, size_t ws_size,
                              hipStream_t stream) {
    const float* x    = (const float*)d_in[0];
    const float* ln1w = (const float*)d_in[1];
    const float* ln1b = (const float*)d_in[2];
    const float* wnn  = (const float*)d_in[3];
    const float* ln2w = (const float*)d_in[4];
    const float* ln2b = (const float*)d_in[5];
    const float* w1   = (const float*)d_in[6];
    const float* b1   = (const float*)d_in[7];
    const float* w2   = (const float*)d_in[8];
    const float* b2   = (const float*)d_in[9];
    float* out = (float*)d_out;
    float* ws  = (float*)d_ws;

    float*    Wn  = ws;                          // 20736 floats
    ushort_t* WfP = (ushort_t*)(Wn + 20736);     // 73728 ushorts
    ushort_t* WtP = WfP + 73728;                 // 73728 ushorts
    float*    X   = (float*)(WtP + 73728);       // NELEM floats
    ushort_t* Rg  = (ushort_t*)(X + NELEM);      // NELEM ushorts (bf16 R)
    float*    Hu0 = (float*)(Rg + NELEM);        // NELEM floats
    float*    Hu1 = Hu0 + NELEM;                 // NELEM floats
    float*    SA  = Hu1 + NELEM;                 // 4*NPIX (per-group channel sums)
    float*    SB  = SA + 4*NPIX;                 // 4*NPIX

    wnorm_n_kernel<<<CC_, 256, 0, stream>>>(wnn, Wn);
    wpack_kernel<<<144, 64, 0, stream>>>(Wn, WfP, WtP);
    ln1_kernel<<<NPIX/256, 256, 0, stream>>>(x, ln1w, ln1b, X);
    fill_kernel<<<NELEM/256, 256, 0, stream>>>(Hu0, NELEM, 1.f/CC_);
    fill_kernel<<<(4*NPIX)/256, 256, 0, stream>>>(SA, 4*NPIX, 0.25f);

    for (int it = 0; it < NITER; ++it) {
        const float* HuI  = (it & 1) ? Hu1 : Hu0;
        float*       HuO  = (it & 1) ? Hu0 : Hu1;
        const float* Scur = (it & 1) ? SB : SA;
        float*       Snxt = (it & 1) ? SA : SB;
        ratio_mfma_kernel<<<448, 512, 0, stream>>>(HuI, Scur, WtP, X, Rg);
        update_mfma_kernel<<<448, 512, 0, stream>>>(Rg, HuI, HuO, Scur, Snxt, WfP);
    }
    // 25 iterations: final Hu in Hu1, final S in SB

    resln3_kernel<<<NPIX/256, 256, 0, stream>>>(x, Hu1, SB, ln2w, ln2b, out, X);
    mlp4_kernel<<<NPIX/32, 384, 0, stream>>>(X, w1, b1, w2, b2, out);
}

// Round 9
// 657.594 us; speedup vs baseline: 4.0990x; 1.1833x over previous
//
#include <hip/hip_runtime.h>
#include <math.h>

typedef unsigned short ushort_t;
typedef __attribute__((ext_vector_type(8))) short bhalf8;
typedef __attribute__((ext_vector_type(4))) float floatx4;

// Problem constants
#define NN    8
#define CC_   96
#define HH    56
#define WW    56
#define HWHW  (HH*WW)            // 3136
#define NPIX  (NN*HWHW)          // 25088
#define NELEM (NN*CC_*HWHW)      // 2408448
#define GROUPS 4
#define IG    24                 // channels per group
#define NITER 25
#define EPSV  1e-12f
#define TS    40                 // LDS ic-slot stride (ushorts), 80 B (16B-aligned b128)

// bf16 helpers (RNE)
__device__ __forceinline__ unsigned bf2pack(float a, float b) {
    unsigned ua = __float_as_uint(a), ub = __float_as_uint(b);
    ua += 0x7fffu + ((ua >> 16) & 1u);
    ub += 0x7fffu + ((ub >> 16) & 1u);
    return (ua >> 16) | (ub & 0xffff0000u);
}
__device__ __forceinline__ ushort_t bf1pack(float a) {
    unsigned ua = __float_as_uint(a);
    ua += 0x7fffu + ((ua >> 16) & 1u);
    return (ushort_t)(ua >> 16);
}
__device__ __forceinline__ float bflo(unsigned u) { return __uint_as_float(u << 16); }
__device__ __forceinline__ float bfhi(unsigned u) { return __uint_as_float(u & 0xffff0000u); }

// ---------------------------------------------------------------------------
// Normalize weights -> Wn[96][216] fp32
__global__ void wnorm_n_kernel(const float* __restrict__ w_in, float* __restrict__ Wn) {
    int o = blockIdx.x;
    int t = threadIdx.x;
    float myv = (t < 216) ? fabsf(w_in[o*216 + t]) : 0.f;
    float v = myv;
    #pragma unroll
    for (int off = 32; off; off >>= 1) v += __shfl_down(v, off, 64);
    __shared__ float red[4];
    if ((t & 63) == 0) red[t >> 6] = v;
    __syncthreads();
    float s = red[0] + red[1] + red[2] + red[3];
    if (t < 216) Wn[o*216 + t] = myv / (s + EPSV);
}

// ---------------------------------------------------------------------------
// Pack conv A-fragments (bf16) for MFMA 16x16x32 (verified in round 7).
__global__ void wpack_kernel(const float* __restrict__ Wn,
                             ushort_t* __restrict__ WfP, ushort_t* __restrict__ WtP) {
    int bi = blockIdx.x;             // 144 = 2 sel * 72
    int sel = bi / 72;
    int rem = bi % 72;
    int ot = rem & 1;
    int gt = rem >> 1;               // g*9 + tap
    int g = gt / 9, tap = gt % 9;
    int lane = threadIdx.x;
    int quad = lane >> 4, nn = lane & 15;
    int m = ot*16 + nn;
    ushort_t v[8];
    #pragma unroll
    for (int j = 0; j < 8; ++j) {
        int kc = quad*8 + j;
        float val = 0.f;
        if (m < IG && kc < IG) {
            if (sel == 0) val = Wn[(g*IG + m)*216 + kc*9 + tap];
            else          val = Wn[(g*IG + kc)*216 + m*9 + (8 - tap)];
        }
        v[j] = bf1pack(val);
    }
    ushort_t* dst = (sel ? WtP : WfP) + ((size_t)(gt*2 + ot)*64 + lane)*8;
    *(uint4*)dst = *(uint4*)v;
}

// ---------------------------------------------------------------------------
// Pack MLP weight fragments: w1P B-frags (B[k=ch][n=hidden]), w2P A-frags
// for the swapped GEMM2 (A[m=channel][k=hidden] = w2^T).
__global__ void mlppack_kernel(const float* __restrict__ w1, const float* __restrict__ w2,
                               ushort_t* __restrict__ w1P, ushort_t* __restrict__ w2P) {
    int f = blockIdx.x;              // 144: 72 for w1 (24nt*3ks), 72 for w2 (6mt*12ks)
    int lane = threadIdx.x;
    int quad = lane >> 4, nn = lane & 15;
    ushort_t v[8];
    if (f < 72) {
        int nt = f / 3, ks = f % 3;
        #pragma unroll
        for (int j = 0; j < 8; ++j)
            v[j] = bf1pack(w1[(size_t)(ks*32 + quad*8 + j)*384 + nt*16 + nn]);
        *(uint4*)(w1P + ((size_t)f*64 + lane)*8) = *(uint4*)v;
    } else {
        int f2 = f - 72;
        int mt = f2 / 12, ks = f2 % 12;
        #pragma unroll
        for (int j = 0; j < 8; ++j)
            v[j] = bf1pack(w2[(size_t)(ks*32 + quad*8 + j)*96 + mt*16 + nn]);
        *(uint4*)(w2P + ((size_t)f2*64 + lane)*8) = *(uint4*)v;
    }
}

// ---------------------------------------------------------------------------
// LN1 -> relu -> channel-normalize => Xp (bf16 channel-pairs):
// Xp[((n*4+g)*12 + pr)*HWHW + hw] packs channels c=g*24+2pr, +1.
__global__ void ln1_kernel(const float* __restrict__ x, const float* __restrict__ lw,
                           const float* __restrict__ lb, unsigned* __restrict__ Xp) {
    int p = blockIdx.x * blockDim.x + threadIdx.x;
    if (p >= NPIX) return;
    int n = p / HWHW, hw = p % HWHW;
    const float* xp = x + (size_t)n*CC_*HWHW + hw;
    float s = 0.f, ss = 0.f;
    for (int c = 0; c < CC_; ++c) { float v = xp[(size_t)c*HWHW]; s += v; ss += v*v; }
    float u  = s * (1.f/CC_);
    float var = ss * (1.f/CC_) - u*u;
    float rs = rsqrtf(var + 1e-6f);
    float sr = 0.f;
    for (int c = 0; c < CC_; ++c) {
        float v = xp[(size_t)c*HWHW];
        float a = fmaxf((v-u)*rs*lw[c] + lb[c], 0.f);
        sr += a;
    }
    float inv = 1.f / (sr + EPSV);
    for (int c = 0; c < CC_; c += 2) {
        float v0 = xp[(size_t)c*HWHW];
        float v1 = xp[(size_t)(c+1)*HWHW];
        float a0 = fmaxf((v0-u)*rs*lw[c] + lb[c], 0.f) * inv;
        float a1 = fmaxf((v1-u)*rs*lw[c+1] + lb[c+1], 0.f) * inv;
        int g = c / IG, pr = (c % IG) >> 1;
        Xp[(size_t)((n*4+g)*12 + pr)*HWHW + hw] = bf2pack(a0, a1);
    }
}

// ---------------------------------------------------------------------------
__global__ void fill_kernel(float* __restrict__ p, int n, float v) {
    int i = blockIdx.x * blockDim.x + threadIdx.x;
    if (i < n) p[i] = v;
}

// ---------------------------------------------------------------------------
// Kernel A: R = X / (convT(Hu/S) + EPS) -> Rp (bf16 pairs).
// Block = (n, g, 4-row band, x-half); 512 thr = 8 waves (4 rows x 2 oc-tiles).
// Tile: 6 rows x 30 pos x 32 ch-slots bf16 (ch 24..31 zero).
__global__ __launch_bounds__(512) void ratio_mfma_kernel(
        const float2* __restrict__ Hup, const float* __restrict__ Scur,
        const ushort_t* __restrict__ WtP, const unsigned* __restrict__ Xp,
        unsigned* __restrict__ Rp) {
    __shared__ ushort_t tile[6*30*TS];   // 14400 B
    __shared__ float sinv[180];
    int b    = blockIdx.x;               // 896
    int half = b & 1;
    int t4   = b >> 1;
    int rt   = t4 % 14;
    int g    = (t4 / 14) & 3;
    int n    = t4 / 56;
    int tid  = threadIdx.x;
    int r0   = rt*4;
    int xb   = half*28;
    int planeBase = (n*4 + g)*12;

    if (tid < 180) {
        int r = tid / 30, pos = tid % 30;
        int gr = r0 - 1 + r, gc = xb - 1 + pos;
        float st = 1.f;
        if (gr >= 0 && gr < HH && gc >= 0 && gc < WW) {
            int p = n*HWHW + gr*WW + gc;
            st = Scur[p] + Scur[NPIX+p] + Scur[2*NPIX+p] + Scur[3*NPIX+p];
        }
        sinv[tid] = 1.f / (st + EPSV);
    }
    __syncthreads();

    // stage HuN = Hu*sinv, bf16 pairs; pr2 6,7 -> zero (ch 24..31)
    #pragma unroll
    for (int i = 0; i < 3; ++i) {
        int idx = tid + i*512;
        if (idx < 1440) {
            int pr2 = idx / 180, rem = idx % 180;
            int r = rem / 30, pos = rem % 30;
            int gr = r0 - 1 + r, gc = xb - 1 + pos;
            uint2 pk = {0u, 0u};
            if (pr2 < 6 && gr >= 0 && gr < HH && gc >= 0 && gc < WW) {
                int off = gr*WW + gc;
                float2 a = Hup[(size_t)(planeBase + 2*pr2)*HWHW + off];
                float2 c = Hup[(size_t)(planeBase + 2*pr2 + 1)*HWHW + off];
                float si = sinv[rem];
                pk.x = bf2pack(a.x*si, a.y*si);
                pk.y = bf2pack(c.x*si, c.y*si);
            }
            *(uint2*)&tile[rem*TS + 4*pr2] = pk;
        }
    }
    __syncthreads();

    int waveId = tid >> 6, lane = tid & 63;
    int w  = waveId & 3;                 // row in band
    int ot = waveId >> 2;                // oc-tile
    int quad = lane >> 4, nn = lane & 15;

    const ushort_t* ap = WtP + ((size_t)(g*9*2 + ot)*64 + lane)*8;
    bhalf8 afr[9];
    #pragma unroll
    for (int t = 0; t < 9; ++t) afr[t] = *(const bhalf8*)(ap + (size_t)t*2*64*8);

    floatx4 acc[2];
    acc[0] = (floatx4){0.f,0.f,0.f,0.f};
    acc[1] = (floatx4){0.f,0.f,0.f,0.f};
    const int x0s[2] = {0, 12};

    #pragma unroll
    for (int t = 0; t < 9; ++t) {
        int ky = t / 3, kx = t % 3;
        int rbase = (w + ky)*30 + kx + nn;
        #pragma unroll
        for (int pt = 0; pt < 2; ++pt) {
            bhalf8 bfr = *(const bhalf8*)&tile[(rbase + x0s[pt])*TS + quad*8];
            acc[pt] = __builtin_amdgcn_mfma_f32_16x16x32_bf16(afr[t], bfr, acc[pt], 0, 0, 0);
        }
    }

    int grow = r0 + w;
    int mb = ot*16 + quad*4;
    if (mb < IG) {
        int pb = planeBase + (mb >> 1);
        #pragma unroll
        for (int pt = 0; pt < 2; ++pt) {
            int off = grow*WW + xb + x0s[pt] + nn;
            unsigned xa = Xp[(size_t)pb*HWHW + off];
            unsigned xc = Xp[(size_t)(pb+1)*HWHW + off];
            Rp[(size_t)pb*HWHW + off] =
                bf2pack(bflo(xa)/(acc[pt][0]+EPSV), bfhi(xa)/(acc[pt][1]+EPSV));
            Rp[(size_t)(pb+1)*HWHW + off] =
                bf2pack(bflo(xc)/(acc[pt][2]+EPSV), bfhi(xc)/(acc[pt][3]+EPSV));
        }
    }
}

// ---------------------------------------------------------------------------
// Kernel B: h = (Hu/S) * conv(R); HuO = h (fp32 pairs); Snxt[g] = sum_c h.
__global__ __launch_bounds__(512) void update_mfma_kernel(
        const unsigned* __restrict__ Rp, const float2* __restrict__ HupI,
        float2* __restrict__ HupO, const float* __restrict__ Scur,
        float* __restrict__ Snxt, const ushort_t* __restrict__ WfP) {
    __shared__ ushort_t tile[6*30*TS];
    __shared__ float sinv2[112];
    __shared__ float sacc[224];
    int b    = blockIdx.x;
    int half = b & 1;
    int t4   = b >> 1;
    int rt   = t4 % 14;
    int g    = (t4 / 14) & 3;
    int n    = t4 / 56;
    int tid  = threadIdx.x;
    int r0   = rt*4;
    int xb   = half*28;
    int planeBase = (n*4 + g)*12;

    if (tid < 112) {
        int p = n*HWHW + (r0 + tid/28)*WW + xb + (tid % 28);
        float st = Scur[p] + Scur[NPIX+p] + Scur[2*NPIX+p] + Scur[3*NPIX+p];
        sinv2[tid] = 1.f / (st + EPSV);
    }

    // stage R tile (pure bf16 copy)
    #pragma unroll
    for (int i = 0; i < 3; ++i) {
        int idx = tid + i*512;
        if (idx < 1440) {
            int pr2 = idx / 180, rem = idx % 180;
            int r = rem / 30, pos = rem % 30;
            int gr = r0 - 1 + r, gc = xb - 1 + pos;
            uint2 pk = {0u, 0u};
            if (pr2 < 6 && gr >= 0 && gr < HH && gc >= 0 && gc < WW) {
                int off = gr*WW + gc;
                pk.x = Rp[(size_t)(planeBase + 2*pr2)*HWHW + off];
                pk.y = Rp[(size_t)(planeBase + 2*pr2 + 1)*HWHW + off];
            }
            *(uint2*)&tile[rem*TS + 4*pr2] = pk;
        }
    }
    __syncthreads();

    int waveId = tid >> 6, lane = tid & 63;
    int w  = waveId & 3;
    int ot = waveId >> 2;
    int quad = lane >> 4, nn = lane & 15;

    const ushort_t* ap = WfP + ((size_t)(g*9*2 + ot)*64 + lane)*8;
    bhalf8 afr[9];
    #pragma unroll
    for (int t = 0; t < 9; ++t) afr[t] = *(const bhalf8*)(ap + (size_t)t*2*64*8);

    floatx4 acc[2];
    acc[0] = (floatx4){0.f,0.f,0.f,0.f};
    acc[1] = (floatx4){0.f,0.f,0.f,0.f};
    const int x0s[2] = {0, 12};

    #pragma unroll
    for (int t = 0; t < 9; ++t) {
        int ky = t / 3, kx = t % 3;
        int rbase = (w + ky)*30 + kx + nn;
        #pragma unroll
        for (int pt = 0; pt < 2; ++pt) {
            bhalf8 bfr = *(const bhalf8*)&tile[(rbase + x0s[pt])*TS + quad*8];
            acc[pt] = __builtin_amdgcn_mfma_f32_16x16x32_bf16(afr[t], bfr, acc[pt], 0, 0, 0);
        }
    }

    int grow = r0 + w;
    int mb = ot*16 + quad*4;
    #pragma unroll
    for (int pt = 0; pt < 2; ++pt) {
        float psum = 0.f;
        int pxh = x0s[pt] + nn;          // 0..27 in-half
        if (mb < IG) {
            int pb = planeBase + (mb >> 1);
            int off = grow*WW + xb + pxh;
            float si = sinv2[w*28 + pxh];
            float2 ha = HupI[(size_t)pb*HWHW + off];
            float2 hc = HupI[(size_t)(pb+1)*HWHW + off];
            float h0 = ha.x * si * acc[pt][0];
            float h1 = ha.y * si * acc[pt][1];
            float h2 = hc.x * si * acc[pt][2];
            float h3 = hc.y * si * acc[pt][3];
            HupO[(size_t)pb*HWHW + off]     = (float2){h0, h1};
            HupO[(size_t)(pb+1)*HWHW + off] = (float2){h2, h3};
            psum = h0 + h1 + h2 + h3;
        }
        psum += __shfl_down(psum, 32, 64);
        psum += __shfl_down(psum, 16, 64);
        if (lane < 16) sacc[ot*112 + w*28 + pxh] = psum;
    }
    __syncthreads();
    if (tid < 112) {
        Snxt[(size_t)g*NPIX + n*HWHW + (r0 + tid/28)*WW + xb + (tid % 28)]
            = sacc[tid] + sacc[112 + tid];
    }
}

// ---------------------------------------------------------------------------
// out = x + Hu/(S+EPS); XLNt[px][96] bf16-pairs = LN_cf(out) (eps 1e-5)
__global__ void resln4_kernel(const float* __restrict__ x, const float2* __restrict__ Hup,
                              const float* __restrict__ S4,
                              const float* __restrict__ lw, const float* __restrict__ lb,
                              float* __restrict__ out, unsigned* __restrict__ XLNt) {
    int p = blockIdx.x * blockDim.x + threadIdx.x;
    if (p >= NPIX) return;
    int n = p / HWHW, hw = p % HWHW;
    size_t base = (size_t)n*CC_*HWHW + hw;
    float stot = S4[p] + S4[NPIX+p] + S4[2*NPIX+p] + S4[3*NPIX+p];
    float sinv = 1.f / (stot + EPSV);
    float s = 0.f, ss = 0.f;
    for (int c = 0; c < CC_; c += 2) {
        int g = c / IG, pr = (c % IG) >> 1;
        float2 hu = Hup[(size_t)((n*4+g)*12 + pr)*HWHW + hw];
        float v0 = x[base + (size_t)c*HWHW]     + hu.x * sinv;
        float v1 = x[base + (size_t)(c+1)*HWHW] + hu.y * sinv;
        out[base + (size_t)c*HWHW]     = v0;
        out[base + (size_t)(c+1)*HWHW] = v1;
        s += v0 + v1; ss += v0*v0 + v1*v1;
    }
    float u  = s * (1.f/CC_);
    float var = ss * (1.f/CC_) - u*u;
    float rs = rsqrtf(var + 1e-5f);
    for (int c = 0; c < CC_; c += 2) {
        float v0 = out[base + (size_t)c*HWHW];
        float v1 = out[base + (size_t)(c+1)*HWHW];
        float a0 = (v0-u)*rs*lw[c]   + lb[c];
        float a1 = (v1-u)*rs*lw[c+1] + lb[c+1];
        XLNt[(size_t)p*48 + (c >> 1)] = bf2pack(a0, a1);
    }
}

// ---------------------------------------------------------------------------
// MFMA MLP: 16 tokens/block, 128 thr (2 waves). GEMM1: wave w does hidden
// nt = w*12..+11; h -> LDS [token][hidden]. GEMM2 swapped (out^T = w2^T h^T):
// wave w does channels mt = w*3..+2; D cols = tokens -> coalesced RMW.
__global__ __launch_bounds__(128) void mlp5_kernel(
        const ushort_t* __restrict__ XLNt, const ushort_t* __restrict__ w1P,
        const float* __restrict__ b1, const ushort_t* __restrict__ w2P,
        const float* __restrict__ b2, float* __restrict__ out) {
    __shared__ ushort_t lh[16*392];      // 12544 B
    int blk = blockIdx.x;                // 1568
    int tid = threadIdx.x;
    int wv  = tid >> 6, lane = tid & 63;
    int quad = lane >> 4, nn = lane & 15;
    int p0  = blk * 16;
    int n   = p0 / HWHW;
    int hw0 = p0 % HWHW;

    // A-frags: X rows for 16 tokens
    const ushort_t* xrow = XLNt + (size_t)(p0 + nn)*96 + quad*8;
    bhalf8 a1[3];
    #pragma unroll
    for (int ks = 0; ks < 3; ++ks) a1[ks] = *(const bhalf8*)(xrow + ks*32);

    // GEMM1 + GELU
    #pragma unroll 1
    for (int i = 0; i < 12; ++i) {
        int nt = wv*12 + i;
        floatx4 acc = (floatx4){0.f,0.f,0.f,0.f};
        #pragma unroll
        for (int ks = 0; ks < 3; ++ks) {
            bhalf8 bfr = *(const bhalf8*)(w1P + ((size_t)(nt*3 + ks)*64 + lane)*8);
            acc = __builtin_amdgcn_mfma_f32_16x16x32_bf16(a1[ks], bfr, acc, 0, 0, 0);
        }
        float b1v = b1[nt*16 + nn];
        #pragma unroll
        for (int r = 0; r < 4; ++r) {
            float h = acc[r] + b1v;
            h = 0.5f * h * (1.f + erff(h * 0.70710678118654752440f));
            lh[(quad*4 + r)*392 + nt*16 + nn] = bf1pack(h);
        }
    }
    __syncthreads();

    // GEMM2: B-frags from lh (tokens), A-frags = packed w2^T
    bhalf8 bf2[12];
    #pragma unroll
    for (int ks = 0; ks < 12; ++ks)
        bf2[ks] = *(const bhalf8*)&lh[nn*392 + ks*32 + quad*8];

    #pragma unroll 1
    for (int i = 0; i < 3; ++i) {
        int mt = wv*3 + i;
        floatx4 acc = (floatx4){0.f,0.f,0.f,0.f};
        #pragma unroll
        for (int ks = 0; ks < 12; ++ks) {
            bhalf8 af = *(const bhalf8*)(w2P + ((size_t)(mt*12 + ks)*64 + lane)*8);
            acc = __builtin_amdgcn_mfma_f32_16x16x32_bf16(af, bf2[ks], acc, 0, 0, 0);
        }
        #pragma unroll
        for (int r = 0; r < 4; ++r) {
            int c = mt*16 + quad*4 + r;
            size_t addr = ((size_t)n*CC_ + c)*HWHW + hw0 + nn;
            out[addr] += acc[r] + b2[c];
        }
    }
}

// ---------------------------------------------------------------------------
extern "C" void kernel_launch(void* const* d_in, const int* in_sizes, int n_in,
                              void* d_out, int out_size, void* d_ws, size_t ws_size,
                              hipStream_t stream) {
    const float* x    = (const float*)d_in[0];
    const float* ln1w = (const float*)d_in[1];
    const float* ln1b = (const float*)d_in[2];
    const float* wnn  = (const float*)d_in[3];
    const float* ln2w = (const float*)d_in[4];
    const float* ln2b = (const float*)d_in[5];
    const float* w1   = (const float*)d_in[6];
    const float* b1   = (const float*)d_in[7];
    const float* w2   = (const float*)d_in[8];
    const float* b2   = (const float*)d_in[9];
    float* out = (float*)d_out;
    char* ws = (char*)d_ws;

    float*    Wn   = (float*)ws;                      ws += 20736*4;
    ushort_t* WfP  = (ushort_t*)ws;                   ws += 73728*2;
    ushort_t* WtP  = (ushort_t*)ws;                   ws += 73728*2;
    ushort_t* w1P  = (ushort_t*)ws;                   ws += 36864*2;
    ushort_t* w2P  = (ushort_t*)ws;                   ws += 36864*2;
    unsigned* Xp   = (unsigned*)ws;                   ws += (size_t)(NELEM/2)*4;
    unsigned* Rp   = (unsigned*)ws;                   ws += (size_t)(NELEM/2)*4;
    float*    Hu0  = (float*)ws;                      ws += (size_t)NELEM*4;
    float*    Hu1  = (float*)ws;                      ws += (size_t)NELEM*4;
    float*    SA   = (float*)ws;                      ws += (size_t)4*NPIX*4;
    float*    SB   = (float*)ws;                      ws += (size_t)4*NPIX*4;
    unsigned* XLNt = (unsigned*)ws;                   ws += (size_t)NPIX*48*4;

    wnorm_n_kernel<<<CC_, 256, 0, stream>>>(wnn, Wn);
    wpack_kernel<<<144, 64, 0, stream>>>(Wn, WfP, WtP);
    mlppack_kernel<<<144, 64, 0, stream>>>(w1, w2, w1P, w2P);
    ln1_kernel<<<NPIX/256, 256, 0, stream>>>(x, ln1w, ln1b, Xp);
    fill_kernel<<<NELEM/256, 256, 0, stream>>>(Hu0, NELEM, 1.f/CC_);
    fill_kernel<<<(4*NPIX)/256, 256, 0, stream>>>(SA, 4*NPIX, 0.25f);

    for (int it = 0; it < NITER; ++it) {
        const float2* HuI  = (const float2*)((it & 1) ? Hu1 : Hu0);
        float2*       HuO  = (float2*)((it & 1) ? Hu0 : Hu1);
        const float*  Scur = (it & 1) ? SB : SA;
        float*        Snxt = (it & 1) ? SA : SB;
        ratio_mfma_kernel<<<896, 512, 0, stream>>>(HuI, Scur, WtP, Xp, Rp);
        update_mfma_kernel<<<896, 512, 0, stream>>>(Rp, HuI, HuO, Scur, Snxt, WfP);
    }
    // 25 iterations: final Hu in Hu1, final S in SB

    resln4_kernel<<<NPIX/256, 256, 0, stream>>>(x, (const float2*)Hu1, SB,
                                                ln2w, ln2b, out, XLNt);
    mlp5_kernel<<<NPIX/16, 128, 0, stream>>>((const ushort_t*)XLNt, w1P, b1, w2P, b2, out);
}

// Round 10
// 633.921 us; speedup vs baseline: 4.2520x; 1.0373x over previous
//
#include <hip/hip_runtime.h>
#include <math.h>

typedef unsigned short ushort_t;
typedef __attribute__((ext_vector_type(8))) short bhalf8;
typedef __attribute__((ext_vector_type(4))) float floatx4;

// Problem constants
#define NN    8
#define CC_   96
#define HH    56
#define WW    56
#define HWHW  (HH*WW)            // 3136
#define NPIX  (NN*HWHW)          // 25088
#define NELEM (NN*CC_*HWHW)      // 2408448
#define GROUPS 4
#define IG    24                 // channels per group
#define NITER 25
#define EPSV  1e-12f
#define TS    40                 // LDS ch-slot stride (ushorts) = 80 B

// bf16 helpers (RNE)
__device__ __forceinline__ unsigned bf2pack(float a, float b) {
    unsigned ua = __float_as_uint(a), ub = __float_as_uint(b);
    ua += 0x7fffu + ((ua >> 16) & 1u);
    ub += 0x7fffu + ((ub >> 16) & 1u);
    return (ua >> 16) | (ub & 0xffff0000u);
}
__device__ __forceinline__ ushort_t bf1pack(float a) {
    unsigned ua = __float_as_uint(a);
    ua += 0x7fffu + ((ua >> 16) & 1u);
    return (ushort_t)(ua >> 16);
}
__device__ __forceinline__ float bflo(unsigned u) { return __uint_as_float(u << 16); }
__device__ __forceinline__ float bfhi(unsigned u) { return __uint_as_float(u & 0xffff0000u); }

// ---------------------------------------------------------------------------
// Normalize weights -> Wn[96][216] fp32
__global__ void wnorm_n_kernel(const float* __restrict__ w_in, float* __restrict__ Wn) {
    int o = blockIdx.x;
    int t = threadIdx.x;
    float myv = (t < 216) ? fabsf(w_in[o*216 + t]) : 0.f;
    float v = myv;
    #pragma unroll
    for (int off = 32; off; off >>= 1) v += __shfl_down(v, off, 64);
    __shared__ float red[4];
    if ((t & 63) == 0) red[t >> 6] = v;
    __syncthreads();
    float s = red[0] + red[1] + red[2] + red[3];
    if (t < 216) Wn[o*216 + t] = myv / (s + EPSV);
}

// ---------------------------------------------------------------------------
// Pack conv A-fragments (bf16) for MFMA 16x16x32 (verified round 7/9).
__global__ void wpack_kernel(const float* __restrict__ Wn,
                             ushort_t* __restrict__ WfP, ushort_t* __restrict__ WtP) {
    int bi = blockIdx.x;             // 144 = 2 sel * 72
    int sel = bi / 72;
    int rem = bi % 72;
    int ot = rem & 1;
    int gt = rem >> 1;               // g*9 + tap
    int g = gt / 9, tap = gt % 9;
    int lane = threadIdx.x;
    int quad = lane >> 4, nn = lane & 15;
    int m = ot*16 + nn;
    ushort_t v[8];
    #pragma unroll
    for (int j = 0; j < 8; ++j) {
        int kc = quad*8 + j;
        float val = 0.f;
        if (m < IG && kc < IG) {
            if (sel == 0) val = Wn[(g*IG + m)*216 + kc*9 + tap];
            else          val = Wn[(g*IG + kc)*216 + m*9 + (8 - tap)];
        }
        v[j] = bf1pack(val);
    }
    ushort_t* dst = (sel ? WtP : WfP) + ((size_t)(gt*2 + ot)*64 + lane)*8;
    *(uint4*)dst = *(uint4*)v;
}

// ---------------------------------------------------------------------------
// Pack MLP weight fragments (verified round 9).
__global__ void mlppack_kernel(const float* __restrict__ w1, const float* __restrict__ w2,
                               ushort_t* __restrict__ w1P, ushort_t* __restrict__ w2P) {
    int f = blockIdx.x;              // 144: 72 for w1 (24nt*3ks), 72 for w2 (6mt*12ks)
    int lane = threadIdx.x;
    int quad = lane >> 4, nn = lane & 15;
    ushort_t v[8];
    if (f < 72) {
        int nt = f / 3, ks = f % 3;
        #pragma unroll
        for (int j = 0; j < 8; ++j)
            v[j] = bf1pack(w1[(size_t)(ks*32 + quad*8 + j)*384 + nt*16 + nn]);
        *(uint4*)(w1P + ((size_t)f*64 + lane)*8) = *(uint4*)v;
    } else {
        int f2 = f - 72;
        int mt = f2 / 12, ks = f2 % 12;
        #pragma unroll
        for (int j = 0; j < 8; ++j)
            v[j] = bf1pack(w2[(size_t)(ks*32 + quad*8 + j)*96 + mt*16 + nn]);
        *(uint4*)(w2P + ((size_t)f2*64 + lane)*8) = *(uint4*)v;
    }
}

// ---------------------------------------------------------------------------
// LN1 -> relu -> channel-normalize => Xp (bf16 channel-pairs).
__global__ void ln1_kernel(const float* __restrict__ x, const float* __restrict__ lw,
                           const float* __restrict__ lb, unsigned* __restrict__ Xp) {
    int p = blockIdx.x * blockDim.x + threadIdx.x;
    if (p >= NPIX) return;
    int n = p / HWHW, hw = p % HWHW;
    const float* xp = x + (size_t)n*CC_*HWHW + hw;
    float s = 0.f, ss = 0.f;
    for (int c = 0; c < CC_; ++c) { float v = xp[(size_t)c*HWHW]; s += v; ss += v*v; }
    float u  = s * (1.f/CC_);
    float var = ss * (1.f/CC_) - u*u;
    float rs = rsqrtf(var + 1e-6f);
    float sr = 0.f;
    for (int c = 0; c < CC_; ++c) {
        float v = xp[(size_t)c*HWHW];
        float a = fmaxf((v-u)*rs*lw[c] + lb[c], 0.f);
        sr += a;
    }
    float inv = 1.f / (sr + EPSV);
    for (int c = 0; c < CC_; c += 2) {
        float v0 = xp[(size_t)c*HWHW];
        float v1 = xp[(size_t)(c+1)*HWHW];
        float a0 = fmaxf((v0-u)*rs*lw[c] + lb[c], 0.f) * inv;
        float a1 = fmaxf((v1-u)*rs*lw[c+1] + lb[c+1], 0.f) * inv;
        int g = c / IG, pr = (c % IG) >> 1;
        Xp[(size_t)((n*4+g)*12 + pr)*HWHW + hw] = bf2pack(a0, a1);
    }
}

// ---------------------------------------------------------------------------
__global__ void fill_kernel(float* __restrict__ p, int n, float v) {
    int i = blockIdx.x * blockDim.x + threadIdx.x;
    if (i < n) p[i] = v;
}

// ---------------------------------------------------------------------------
// Fused NNMF iteration (MFMA). Block = (n, g, 4-row out band, x-half).
// 512 thr = 8 waves.
// Phase A: stage HuN = Hu/S, 8 rows x 32 pos halo tile (bf16, ch-pads zeroed);
//          zero R tile ch-slots 24..31.
// Phase B (convT): 12 tasks (6 R-rows x 2 oc-tiles) over 8 waves; 2 x-tiles
//          (x0R = 0, 14) cover 30 px; epilogue R = X/(acc+eps) written to the
//          separate R LDS region (no aliasing with HuN).
// Phase C (forward conv): 8 waves = 4 rows x 2 oc-tiles, x0F = {0,12} -> 28 px;
//          h = (Hu/S)*acc; HuO = h; channel sums -> Snxt (plain stores).
__global__ __launch_bounds__(512) void nnmf_mfma_kernel(
        const float2* __restrict__ HupI, float2* __restrict__ HupO,
        const float* __restrict__ Scur, float* __restrict__ Snxt,
        const ushort_t* __restrict__ WtP, const ushort_t* __restrict__ WfP,
        const unsigned* __restrict__ Xp) {
    __shared__ ushort_t hn[256*TS];      // HuN tile [row8*32+pos][40]   20480 B
    __shared__ ushort_t rt_[192*TS];     // R   tile [row6*32+pos][40]   15360 B
    __shared__ float sinv[256];
    __shared__ float sacc[224];
    int b    = blockIdx.x;               // 896
    int half = b & 1;
    int t4   = b >> 1;
    int rtb  = t4 % 14;
    int g    = (t4 / 14) & 3;
    int n    = t4 / 56;
    int tid  = threadIdx.x;
    int r0   = rtb*4;
    int xb   = half*28;
    int planeBase = (n*4 + g)*12;

    // ---- sinv for the 8x32 staging grid (gr = r0-2+r, gc = xb-2+q)
    if (tid < 256) {
        int r = tid >> 5, q = tid & 31;
        int gr = r0 - 2 + r, gc = xb - 2 + q;
        float st = 1.f;
        if (gr >= 0 && gr < HH && gc >= 0 && gc < WW) {
            int p = n*HWHW + gr*WW + gc;
            st = Scur[p] + Scur[NPIX+p] + Scur[2*NPIX+p] + Scur[3*NPIX+p];
        }
        sinv[tid] = 1.f / (st + EPSV);
    }
    __syncthreads();

    // ---- stage HuN; zero R ch-slots 24..31
    for (int idx = tid; idx < 2048; idx += 512) {
        int pr2  = idx >> 8;             // 0..7 (6 used)
        int slot = idx & 255;
        int r = slot >> 5, q = slot & 31;
        int gr = r0 - 2 + r, gc = xb - 2 + q;
        uint2 pk = {0u, 0u};
        if (pr2 < 6 && gr >= 0 && gr < HH && gc >= 0 && gc < WW) {
            int off = gr*WW + gc;
            float2 a = HupI[(size_t)(planeBase + 2*pr2)*HWHW + off];
            float2 c = HupI[(size_t)(planeBase + 2*pr2 + 1)*HWHW + off];
            float si = sinv[slot];
            pk.x = bf2pack(a.x*si, a.y*si);
            pk.y = bf2pack(c.x*si, c.y*si);
        }
        *(uint2*)&hn[slot*TS + 4*pr2] = pk;
    }
    if (tid < 192) *(uint4*)&rt_[tid*TS + 24] = (uint4){0u,0u,0u,0u};
    __syncthreads();

    int waveId = tid >> 6, lane = tid & 63;
    int quad = lane >> 4, nn = lane & 15;

    // ---- Phase B: convT -> R band (6 rows x 30 px) in LDS
    {
        int ot = waveId & 1;
        const ushort_t* ap = WtP + ((size_t)(g*9*2 + ot)*64 + lane)*8;
        bhalf8 afr[9];
        #pragma unroll
        for (int t = 0; t < 9; ++t) afr[t] = *(const bhalf8*)(ap + (size_t)t*2*64*8);
        int mb = ot*16 + quad*4;

        #pragma unroll 1
        for (int tk = waveId; tk < 12; tk += 8) {
            int row = tk >> 1;           // 0..5 (gr = r0-1+row)
            #pragma unroll
            for (int pt = 0; pt < 2; ++pt) {
                int x0R = pt*14;
                floatx4 acc = (floatx4){0.f,0.f,0.f,0.f};
                #pragma unroll
                for (int t = 0; t < 9; ++t) {
                    int ky = t / 3, kx = t % 3;
                    bhalf8 bfr = *(const bhalf8*)
                        &hn[((row + ky)*32 + kx + nn + x0R)*TS + quad*8];
                    acc = __builtin_amdgcn_mfma_f32_16x16x32_bf16(afr[t], bfr, acc, 0, 0, 0);
                }
                if (mb < IG) {
                    int gr = r0 - 1 + row, gc = xb - 1 + x0R + nn;
                    unsigned xa = 0u, xc = 0u;
                    if (gr >= 0 && gr < HH && gc >= 0 && gc < WW) {
                        int off = gr*WW + gc;
                        int pb = planeBase + (mb >> 1);
                        xa = Xp[(size_t)pb*HWHW + off];
                        xc = Xp[(size_t)(pb+1)*HWHW + off];
                    }
                    int slot = row*32 + x0R + nn;
                    *(unsigned*)&rt_[slot*TS + mb] =
                        bf2pack(bflo(xa)/(acc[0]+EPSV), bfhi(xa)/(acc[1]+EPSV));
                    *(unsigned*)&rt_[slot*TS + mb + 2] =
                        bf2pack(bflo(xc)/(acc[2]+EPSV), bfhi(xc)/(acc[3]+EPSV));
                }
            }
        }
    }
    __syncthreads();

    // ---- Phase C: forward conv + multiplicative update
    {
        int w  = waveId & 3;             // out row in band
        int ot = waveId >> 2;
        const ushort_t* ap = WfP + ((size_t)(g*9*2 + ot)*64 + lane)*8;
        bhalf8 afr[9];
        #pragma unroll
        for (int t = 0; t < 9; ++t) afr[t] = *(const bhalf8*)(ap + (size_t)t*2*64*8);

        floatx4 acc[2];
        acc[0] = (floatx4){0.f,0.f,0.f,0.f};
        acc[1] = (floatx4){0.f,0.f,0.f,0.f};
        #pragma unroll
        for (int t = 0; t < 9; ++t) {
            int ky = t / 3, kx = t % 3;
            #pragma unroll
            for (int pt = 0; pt < 2; ++pt) {
                bhalf8 bfr = *(const bhalf8*)
                    &rt_[((w + ky)*32 + kx + nn + pt*12)*TS + quad*8];
                acc[pt] = __builtin_amdgcn_mfma_f32_16x16x32_bf16(afr[t], bfr, acc[pt], 0, 0, 0);
            }
        }

        int grow = r0 + w;
        int mb = ot*16 + quad*4;
        #pragma unroll
        for (int pt = 0; pt < 2; ++pt) {
            int pxh = pt*12 + nn;        // 0..27
            float psum = 0.f;
            if (mb < IG) {
                int off = grow*WW + xb + pxh;
                float si = sinv[(w + 2)*32 + pxh + 2];
                int pb = planeBase + (mb >> 1);
                float2 ha = HupI[(size_t)pb*HWHW + off];
                float2 hc = HupI[(size_t)(pb+1)*HWHW + off];
                float h0 = ha.x * si * acc[pt][0];
                float h1 = ha.y * si * acc[pt][1];
                float h2 = hc.x * si * acc[pt][2];
                float h3 = hc.y * si * acc[pt][3];
                HupO[(size_t)pb*HWHW + off]     = (float2){h0, h1};
                HupO[(size_t)(pb+1)*HWHW + off] = (float2){h2, h3};
                psum = h0 + h1 + h2 + h3;
            }
            psum += __shfl_down(psum, 32, 64);
            psum += __shfl_down(psum, 16, 64);
            if (lane < 16) sacc[ot*112 + w*28 + pxh] = psum;
        }
    }
    __syncthreads();
    if (tid < 112) {
        Snxt[(size_t)g*NPIX + n*HWHW + (r0 + tid/28)*WW + xb + (tid % 28)]
            = sacc[tid] + sacc[112 + tid];
    }
}

// ---------------------------------------------------------------------------
// out = x + Hu/(S+EPS); XLNt[px][96] bf16-pairs = LN_cf(out) (eps 1e-5)
__global__ void resln4_kernel(const float* __restrict__ x, const float2* __restrict__ Hup,
                              const float* __restrict__ S4,
                              const float* __restrict__ lw, const float* __restrict__ lb,
                              float* __restrict__ out, unsigned* __restrict__ XLNt) {
    int p = blockIdx.x * blockDim.x + threadIdx.x;
    if (p >= NPIX) return;
    int n = p / HWHW, hw = p % HWHW;
    size_t base = (size_t)n*CC_*HWHW + hw;
    float stot = S4[p] + S4[NPIX+p] + S4[2*NPIX+p] + S4[3*NPIX+p];
    float sinv = 1.f / (stot + EPSV);
    float s = 0.f, ss = 0.f;
    for (int c = 0; c < CC_; c += 2) {
        int g = c / IG, pr = (c % IG) >> 1;
        float2 hu = Hup[(size_t)((n*4+g)*12 + pr)*HWHW + hw];
        float v0 = x[base + (size_t)c*HWHW]     + hu.x * sinv;
        float v1 = x[base + (size_t)(c+1)*HWHW] + hu.y * sinv;
        out[base + (size_t)c*HWHW]     = v0;
        out[base + (size_t)(c+1)*HWHW] = v1;
        s += v0 + v1; ss += v0*v0 + v1*v1;
    }
    float u  = s * (1.f/CC_);
    float var = ss * (1.f/CC_) - u*u;
    float rs = rsqrtf(var + 1e-5f);
    for (int c = 0; c < CC_; c += 2) {
        float v0 = out[base + (size_t)c*HWHW];
        float v1 = out[base + (size_t)(c+1)*HWHW];
        float a0 = (v0-u)*rs*lw[c]   + lb[c];
        float a1 = (v1-u)*rs*lw[c+1] + lb[c+1];
        XLNt[(size_t)p*48 + (c >> 1)] = bf2pack(a0, a1);
    }
}

// ---------------------------------------------------------------------------
// MFMA MLP (verified round 9): 16 tokens/block, 128 thr.
__global__ __launch_bounds__(128) void mlp5_kernel(
        const ushort_t* __restrict__ XLNt, const ushort_t* __restrict__ w1P,
        const float* __restrict__ b1, const ushort_t* __restrict__ w2P,
        const float* __restrict__ b2, float* __restrict__ out) {
    __shared__ ushort_t lh[16*392];      // 12544 B
    int blk = blockIdx.x;                // 1568
    int tid = threadIdx.x;
    int wv  = tid >> 6, lane = tid & 63;
    int quad = lane >> 4, nn = lane & 15;
    int p0  = blk * 16;
    int n   = p0 / HWHW;
    int hw0 = p0 % HWHW;

    const ushort_t* xrow = XLNt + (size_t)(p0 + nn)*96 + quad*8;
    bhalf8 a1[3];
    #pragma unroll
    for (int ks = 0; ks < 3; ++ks) a1[ks] = *(const bhalf8*)(xrow + ks*32);

    #pragma unroll 1
    for (int i = 0; i < 12; ++i) {
        int nt = wv*12 + i;
        floatx4 acc = (floatx4){0.f,0.f,0.f,0.f};
        #pragma unroll
        for (int ks = 0; ks < 3; ++ks) {
            bhalf8 bfr = *(const bhalf8*)(w1P + ((size_t)(nt*3 + ks)*64 + lane)*8);
            acc = __builtin_amdgcn_mfma_f32_16x16x32_bf16(a1[ks], bfr, acc, 0, 0, 0);
        }
        float b1v = b1[nt*16 + nn];
        #pragma unroll
        for (int r = 0; r < 4; ++r) {
            float h = acc[r] + b1v;
            h = 0.5f * h * (1.f + erff(h * 0.70710678118654752440f));
            lh[(quad*4 + r)*392 + nt*16 + nn] = bf1pack(h);
        }
    }
    __syncthreads();

    bhalf8 bf2[12];
    #pragma unroll
    for (int ks = 0; ks < 12; ++ks)
        bf2[ks] = *(const bhalf8*)&lh[nn*392 + ks*32 + quad*8];

    #pragma unroll 1
    for (int i = 0; i < 3; ++i) {
        int mt = wv*3 + i;
        floatx4 acc = (floatx4){0.f,0.f,0.f,0.f};
        #pragma unroll
        for (int ks = 0; ks < 12; ++ks) {
            bhalf8 af = *(const bhalf8*)(w2P + ((size_t)(mt*12 + ks)*64 + lane)*8);
            acc = __builtin_amdgcn_mfma_f32_16x16x32_bf16(af, bf2[ks], acc, 0, 0, 0);
        }
        #pragma unroll
        for (int r = 0; r < 4; ++r) {
            int c = mt*16 + quad*4 + r;
            size_t addr = ((size_t)n*CC_ + c)*HWHW + hw0 + nn;
            out[addr] += acc[r] + b2[c];
        }
    }
}

// ---------------------------------------------------------------------------
extern "C" void kernel_launch(void* const* d_in, const int* in_sizes, int n_in,
                              void* d_out, int out_size, void* d_ws, size_t ws_size,
                              hipStream_t stream) {
    const float* x    = (const float*)d_in[0];
    const float* ln1w = (const float*)d_in[1];
    const float* ln1b = (const float*)d_in[2];
    const float* wnn  = (const float*)d_in[3];
    const float* ln2w = (const float*)d_in[4];
    const float* ln2b = (const float*)d_in[5];
    const float* w1   = (const float*)d_in[6];
    const float* b1   = (const float*)d_in[7];
    const float* w2   = (const float*)d_in[8];
    const float* b2   = (const float*)d_in[9];
    float* out = (float*)d_out;
    char* ws = (char*)d_ws;

    float*    Wn   = (float*)ws;                      ws += 20736*4;
    ushort_t* WfP  = (ushort_t*)ws;                   ws += 73728*2;
    ushort_t* WtP  = (ushort_t*)ws;                   ws += 73728*2;
    ushort_t* w1P  = (ushort_t*)ws;                   ws += 36864*2;
    ushort_t* w2P  = (ushort_t*)ws;                   ws += 36864*2;
    unsigned* Xp   = (unsigned*)ws;                   ws += (size_t)(NELEM/2)*4;
    float*    Hu0  = (float*)ws;                      ws += (size_t)NELEM*4;
    float*    Hu1  = (float*)ws;                      ws += (size_t)NELEM*4;
    float*    SA   = (float*)ws;                      ws += (size_t)4*NPIX*4;
    float*    SB   = (float*)ws;                      ws += (size_t)4*NPIX*4;
    unsigned* XLNt = (unsigned*)ws;                   ws += (size_t)NPIX*48*4;

    wnorm_n_kernel<<<CC_, 256, 0, stream>>>(wnn, Wn);
    wpack_kernel<<<144, 64, 0, stream>>>(Wn, WfP, WtP);
    mlppack_kernel<<<144, 64, 0, stream>>>(w1, w2, w1P, w2P);
    ln1_kernel<<<NPIX/256, 256, 0, stream>>>(x, ln1w, ln1b, Xp);
    fill_kernel<<<NELEM/256, 256, 0, stream>>>(Hu0, NELEM, 1.f/CC_);
    fill_kernel<<<(4*NPIX)/256, 256, 0, stream>>>(SA, 4*NPIX, 0.25f);

    for (int it = 0; it < NITER; ++it) {
        const float2* HuI  = (const float2*)((it & 1) ? Hu1 : Hu0);
        float2*       HuO  = (float2*)((it & 1) ? Hu0 : Hu1);
        const float*  Scur = (it & 1) ? SB : SA;
        float*        Snxt = (it & 1) ? SA : SB;
        nnmf_mfma_kernel<<<896, 512, 0, stream>>>(HuI, HuO, Scur, Snxt, WtP, WfP, Xp);
    }
    // 25 iterations: final Hu in Hu1, final S in SB

    resln4_kernel<<<NPIX/256, 256, 0, stream>>>(x, (const float2*)Hu1, SB,
                                                ln2w, ln2b, out, XLNt);
    mlp5_kernel<<<NPIX/16, 128, 0, stream>>>((const ushort_t*)XLNt, w1P, b1, w2P, b2, out);
}

// Round 11
// 560.412 us; speedup vs baseline: 4.8098x; 1.1312x over previous
//
#include <hip/hip_runtime.h>
#include <math.h>
#include <string.h>

typedef unsigned short ushort_t;
typedef __attribute__((ext_vector_type(8))) short bhalf8;
typedef __attribute__((ext_vector_type(4))) float floatx4;

// Problem constants
#define NN    8
#define CC_   96
#define HH    56
#define WW    56
#define HWHW  (HH*WW)            // 3136
#define NPIX  (NN*HWHW)          // 25088
#define NELEM (NN*CC_*HWHW)      // 2408448
#define GROUPS 4
#define IG    24                 // channels per group
#define NITER 25
#define EPSV  1e-12f
#define TS    40                 // LDS ch-slot stride (ushorts) = 80 B

// bf16 helpers (RNE)
__device__ __forceinline__ unsigned bf2pack(float a, float b) {
    unsigned ua = __float_as_uint(a), ub = __float_as_uint(b);
    ua += 0x7fffu + ((ua >> 16) & 1u);
    ub += 0x7fffu + ((ub >> 16) & 1u);
    return (ua >> 16) | (ub & 0xffff0000u);
}
__device__ __forceinline__ ushort_t bf1pack(float a) {
    unsigned ua = __float_as_uint(a);
    ua += 0x7fffu + ((ua >> 16) & 1u);
    return (ushort_t)(ua >> 16);
}
__device__ __forceinline__ float bflo(unsigned u) { return __uint_as_float(u << 16); }
__device__ __forceinline__ float bfhi(unsigned u) { return __uint_as_float(u & 0xffff0000u); }

// ---------------------------------------------------------------------------
// Normalize weights -> Wn[96][216] fp32
__global__ void wnorm_n_kernel(const float* __restrict__ w_in, float* __restrict__ Wn) {
    int o = blockIdx.x;
    int t = threadIdx.x;
    float myv = (t < 216) ? fabsf(w_in[o*216 + t]) : 0.f;
    float v = myv;
    #pragma unroll
    for (int off = 32; off; off >>= 1) v += __shfl_down(v, off, 64);
    __shared__ float red[4];
    if ((t & 63) == 0) red[t >> 6] = v;
    __syncthreads();
    float s = red[0] + red[1] + red[2] + red[3];
    if (t < 216) Wn[o*216 + t] = myv / (s + EPSV);
}

// ---------------------------------------------------------------------------
// Pack conv A-fragments (bf16) for MFMA 16x16x32 (verified round 7/9).
__global__ void wpack_kernel(const float* __restrict__ Wn,
                             ushort_t* __restrict__ WfP, ushort_t* __restrict__ WtP) {
    int bi = blockIdx.x;             // 144 = 2 sel * 72
    int sel = bi / 72;
    int rem = bi % 72;
    int ot = rem & 1;
    int gt = rem >> 1;               // g*9 + tap
    int g = gt / 9, tap = gt % 9;
    int lane = threadIdx.x;
    int quad = lane >> 4, nn = lane & 15;
    int m = ot*16 + nn;
    ushort_t v[8];
    #pragma unroll
    for (int j = 0; j < 8; ++j) {
        int kc = quad*8 + j;
        float val = 0.f;
        if (m < IG && kc < IG) {
            if (sel == 0) val = Wn[(g*IG + m)*216 + kc*9 + tap];
            else          val = Wn[(g*IG + kc)*216 + m*9 + (8 - tap)];
        }
        v[j] = bf1pack(val);
    }
    ushort_t* dst = (sel ? WtP : WfP) + ((size_t)(gt*2 + ot)*64 + lane)*8;
    *(uint4*)dst = *(uint4*)v;
}

// ---------------------------------------------------------------------------
// Pack MLP weight fragments (verified round 9).
__global__ void mlppack_kernel(const float* __restrict__ w1, const float* __restrict__ w2,
                               ushort_t* __restrict__ w1P, ushort_t* __restrict__ w2P) {
    int f = blockIdx.x;              // 144: 72 for w1 (24nt*3ks), 72 for w2 (6mt*12ks)
    int lane = threadIdx.x;
    int quad = lane >> 4, nn = lane & 15;
    ushort_t v[8];
    if (f < 72) {
        int nt = f / 3, ks = f % 3;
        #pragma unroll
        for (int j = 0; j < 8; ++j)
            v[j] = bf1pack(w1[(size_t)(ks*32 + quad*8 + j)*384 + nt*16 + nn]);
        *(uint4*)(w1P + ((size_t)f*64 + lane)*8) = *(uint4*)v;
    } else {
        int f2 = f - 72;
        int mt = f2 / 12, ks = f2 % 12;
        #pragma unroll
        for (int j = 0; j < 8; ++j)
            v[j] = bf1pack(w2[(size_t)(ks*32 + quad*8 + j)*96 + mt*16 + nn]);
        *(uint4*)(w2P + ((size_t)f2*64 + lane)*8) = *(uint4*)v;
    }
}

// ---------------------------------------------------------------------------
// LN1 -> relu -> channel-normalize => Xp (bf16 channel-pairs).
__global__ void ln1_kernel(const float* __restrict__ x, const float* __restrict__ lw,
                           const float* __restrict__ lb, unsigned* __restrict__ Xp) {
    int p = blockIdx.x * blockDim.x + threadIdx.x;
    if (p >= NPIX) return;
    int n = p / HWHW, hw = p % HWHW;
    const float* xp = x + (size_t)n*CC_*HWHW + hw;
    float s = 0.f, ss = 0.f;
    for (int c = 0; c < CC_; ++c) { float v = xp[(size_t)c*HWHW]; s += v; ss += v*v; }
    float u  = s * (1.f/CC_);
    float var = ss * (1.f/CC_) - u*u;
    float rs = rsqrtf(var + 1e-6f);
    float sr = 0.f;
    for (int c = 0; c < CC_; ++c) {
        float v = xp[(size_t)c*HWHW];
        float a = fmaxf((v-u)*rs*lw[c] + lb[c], 0.f);
        sr += a;
    }
    float inv = 1.f / (sr + EPSV);
    for (int c = 0; c < CC_; c += 2) {
        float v0 = xp[(size_t)c*HWHW];
        float v1 = xp[(size_t)(c+1)*HWHW];
        float a0 = fmaxf((v0-u)*rs*lw[c] + lb[c], 0.f) * inv;
        float a1 = fmaxf((v1-u)*rs*lw[c+1] + lb[c+1], 0.f) * inv;
        int g = c / IG, pr = (c % IG) >> 1;
        Xp[(size_t)((n*4+g)*12 + pr)*HWHW + hw] = bf2pack(a0, a1);
    }
}

// ---------------------------------------------------------------------------
__global__ void fill_kernel(float* __restrict__ p, int n, float v) {
    int i = blockIdx.x * blockDim.x + threadIdx.x;
    if (i < n) p[i] = v;
}
__global__ void fillu_kernel(unsigned* __restrict__ p, int n, unsigned v) {
    int i = blockIdx.x * blockDim.x + threadIdx.x;
    if (i < n) p[i] = v;
}

// ---------------------------------------------------------------------------
// Fused NNMF iteration (MFMA). Block = (n, g, 4-row out band, x-half).
// 512 thr = 8 waves. Hu is packed bf16 channel-pairs (plane layout = Xp).
// Phase A: stage HuN = Hu/S (8 rows x 32 pos, bf16); zero R pad slots.
// Phase B (convT): 24 balanced wave-tasks (6 rows x 2 ot x 2 x-tiles);
//          X operands loaded before the MFMA chain; R -> separate LDS tile.
// Phase C (fwd conv): h = HuN(LDS) * acc; HuO (bf16 packed); chan sums -> Snxt.
__global__ __launch_bounds__(512) void nnmf_mfma_kernel(
        const unsigned* __restrict__ HupI, unsigned* __restrict__ HupO,
        const float* __restrict__ Scur, float* __restrict__ Snxt,
        const ushort_t* __restrict__ WtP, const ushort_t* __restrict__ WfP,
        const unsigned* __restrict__ Xp) {
    __shared__ ushort_t hn[256*TS];      // HuN tile [row8*32+pos][40]   20480 B
    __shared__ ushort_t rt_[192*TS];     // R   tile [row6*32+pos][40]   15360 B
    __shared__ float sinv[256];
    __shared__ float sacc[224];
    int b    = blockIdx.x;               // 896
    int half = b & 1;
    int t4   = b >> 1;
    int rtb  = t4 % 14;
    int g    = (t4 / 14) & 3;
    int n    = t4 / 56;
    int tid  = threadIdx.x;
    int r0   = rtb*4;
    int xb   = half*28;
    int planeBase = (n*4 + g)*12;

    int waveId = tid >> 6, lane = tid & 63;
    int quad = lane >> 4, nn = lane & 15;

    // convT weight frags early: latency overlaps staging
    int otB = waveId & 1;
    bhalf8 afrB[9];
    {
        const ushort_t* ap = WtP + ((size_t)(g*9*2 + otB)*64 + lane)*8;
        #pragma unroll
        for (int t = 0; t < 9; ++t) afrB[t] = *(const bhalf8*)(ap + (size_t)t*2*64*8);
    }

    // ---- sinv for the 8x32 staging grid (gr = r0-2+r, gc = xb-2+q)
    if (tid < 256) {
        int r = tid >> 5, q = tid & 31;
        int gr = r0 - 2 + r, gc = xb - 2 + q;
        float st = 1.f;
        if (gr >= 0 && gr < HH && gc >= 0 && gc < WW) {
            int p = n*HWHW + gr*WW + gc;
            st = Scur[p] + Scur[NPIX+p] + Scur[2*NPIX+p] + Scur[3*NPIX+p];
        }
        sinv[tid] = 1.f / (st + EPSV);
    }
    __syncthreads();

    // ---- stage HuN (bf16 in -> *si -> bf16); zero R ch-slots 24..31
    for (int idx = tid; idx < 2048; idx += 512) {
        int pr2  = idx >> 8;             // 0..7 (6 used)
        int slot = idx & 255;
        int r = slot >> 5, q = slot & 31;
        int gr = r0 - 2 + r, gc = xb - 2 + q;
        uint2 pk = {0u, 0u};
        if (pr2 < 6 && gr >= 0 && gr < HH && gc >= 0 && gc < WW) {
            int off = gr*WW + gc;
            unsigned a = HupI[(size_t)(planeBase + 2*pr2)*HWHW + off];
            unsigned c = HupI[(size_t)(planeBase + 2*pr2 + 1)*HWHW + off];
            float si = sinv[slot];
            pk.x = bf2pack(bflo(a)*si, bfhi(a)*si);
            pk.y = bf2pack(bflo(c)*si, bfhi(c)*si);
        }
        *(uint2*)&hn[slot*TS + 4*pr2] = pk;
    }
    if (tid < 192) *(uint4*)&rt_[tid*TS + 24] = (uint4){0u,0u,0u,0u};
    __syncthreads();

    // ---- Phase B: convT -> R band (6 rows x 30 px) in LDS; 3 tasks/wave
    {
        int mb = otB*16 + quad*4;
        #pragma unroll
        for (int i = 0; i < 3; ++i) {
            int tk  = waveId + 8*i;      // 0..23, ot = tk&1 == otB
            int pt  = (tk >> 1) & 1;
            int row = tk >> 2;           // 0..5 (gr = r0-1+row)
            int x0R = pt*14;
            // hoisted ratio operands
            unsigned xa = 0u, xc = 0u;
            int gr = r0 - 1 + row, gc = xb - 1 + x0R + nn;
            if (mb < IG && gr >= 0 && gr < HH && gc >= 0 && gc < WW) {
                int off = gr*WW + gc;
                int pb = planeBase + (mb >> 1);
                xa = Xp[(size_t)pb*HWHW + off];
                xc = Xp[(size_t)(pb+1)*HWHW + off];
            }
            floatx4 acc = (floatx4){0.f,0.f,0.f,0.f};
            #pragma unroll
            for (int t = 0; t < 9; ++t) {
                int ky = t / 3, kx = t % 3;
                bhalf8 bfr = *(const bhalf8*)
                    &hn[((row + ky)*32 + kx + nn + x0R)*TS + quad*8];
                acc = __builtin_amdgcn_mfma_f32_16x16x32_bf16(afrB[t], bfr, acc, 0, 0, 0);
            }
            if (mb < IG) {
                int slot = row*32 + x0R + nn;
                *(unsigned*)&rt_[slot*TS + mb] =
                    bf2pack(bflo(xa)/(acc[0]+EPSV), bfhi(xa)/(acc[1]+EPSV));
                *(unsigned*)&rt_[slot*TS + mb + 2] =
                    bf2pack(bflo(xc)/(acc[2]+EPSV), bfhi(xc)/(acc[3]+EPSV));
            }
        }
    }
    __syncthreads();

    // ---- Phase C: forward conv + multiplicative update (Hu from LDS)
    {
        int w  = waveId & 3;             // out row in band
        int ot = waveId >> 2;
        const ushort_t* ap = WfP + ((size_t)(g*9*2 + ot)*64 + lane)*8;
        bhalf8 afr[9];
        #pragma unroll
        for (int t = 0; t < 9; ++t) afr[t] = *(const bhalf8*)(ap + (size_t)t*2*64*8);

        floatx4 acc[2];
        acc[0] = (floatx4){0.f,0.f,0.f,0.f};
        acc[1] = (floatx4){0.f,0.f,0.f,0.f};
        #pragma unroll
        for (int t = 0; t < 9; ++t) {
            int ky = t / 3, kx = t % 3;
            #pragma unroll
            for (int pt = 0; pt < 2; ++pt) {
                bhalf8 bfr = *(const bhalf8*)
                    &rt_[((w + ky)*32 + kx + nn + pt*12)*TS + quad*8];
                acc[pt] = __builtin_amdgcn_mfma_f32_16x16x32_bf16(afr[t], bfr, acc[pt], 0, 0, 0);
            }
        }

        int grow = r0 + w;
        int mb = ot*16 + quad*4;
        #pragma unroll
        for (int pt = 0; pt < 2; ++pt) {
            int pxh = pt*12 + nn;        // 0..27
            float psum = 0.f;
            if (mb < IG) {
                int off = grow*WW + xb + pxh;
                int pb = planeBase + (mb >> 1);
                uint2 hv = *(const uint2*)&hn[((w + 2)*32 + pxh + 2)*TS + mb];
                float h0 = bflo(hv.x) * acc[pt][0];
                float h1 = bfhi(hv.x) * acc[pt][1];
                float h2 = bflo(hv.y) * acc[pt][2];
                float h3 = bfhi(hv.y) * acc[pt][3];
                HupO[(size_t)pb*HWHW + off]     = bf2pack(h0, h1);
                HupO[(size_t)(pb+1)*HWHW + off] = bf2pack(h2, h3);
                psum = h0 + h1 + h2 + h3;
            }
            psum += __shfl_down(psum, 32, 64);
            psum += __shfl_down(psum, 16, 64);
            if (lane < 16) sacc[ot*112 + w*28 + pxh] = psum;
        }
    }
    __syncthreads();
    if (tid < 112) {
        Snxt[(size_t)g*NPIX + n*HWHW + (r0 + tid/28)*WW + xb + (tid % 28)]
            = sacc[tid] + sacc[112 + tid];
    }
}

// ---------------------------------------------------------------------------
// out = x + Hu/(S+EPS); XLNt[px][96] bf16-pairs = LN_cf(out) (eps 1e-5)
__global__ void resln4_kernel(const float* __restrict__ x, const unsigned* __restrict__ Hup,
                              const float* __restrict__ S4,
                              const float* __restrict__ lw, const float* __restrict__ lb,
                              float* __restrict__ out, unsigned* __restrict__ XLNt) {
    int p = blockIdx.x * blockDim.x + threadIdx.x;
    if (p >= NPIX) return;
    int n = p / HWHW, hw = p % HWHW;
    size_t base = (size_t)n*CC_*HWHW + hw;
    float stot = S4[p] + S4[NPIX+p] + S4[2*NPIX+p] + S4[3*NPIX+p];
    float sinv = 1.f / (stot + EPSV);
    float s = 0.f, ss = 0.f;
    for (int c = 0; c < CC_; c += 2) {
        int g = c / IG, pr = (c % IG) >> 1;
        unsigned hu = Hup[(size_t)((n*4+g)*12 + pr)*HWHW + hw];
        float v0 = x[base + (size_t)c*HWHW]     + bflo(hu) * sinv;
        float v1 = x[base + (size_t)(c+1)*HWHW] + bfhi(hu) * sinv;
        out[base + (size_t)c*HWHW]     = v0;
        out[base + (size_t)(c+1)*HWHW] = v1;
        s += v0 + v1; ss += v0*v0 + v1*v1;
    }
    float u  = s * (1.f/CC_);
    float var = ss * (1.f/CC_) - u*u;
    float rs = rsqrtf(var + 1e-5f);
    for (int c = 0; c < CC_; c += 2) {
        float v0 = out[base + (size_t)c*HWHW];
        float v1 = out[base + (size_t)(c+1)*HWHW];
        float a0 = (v0-u)*rs*lw[c]   + lb[c];
        float a1 = (v1-u)*rs*lw[c+1] + lb[c+1];
        XLNt[(size_t)p*48 + (c >> 1)] = bf2pack(a0, a1);
    }
}

// ---------------------------------------------------------------------------
// MFMA MLP (verified round 9): 16 tokens/block, 128 thr.
__global__ __launch_bounds__(128) void mlp5_kernel(
        const ushort_t* __restrict__ XLNt, const ushort_t* __restrict__ w1P,
        const float* __restrict__ b1, const ushort_t* __restrict__ w2P,
        const float* __restrict__ b2, float* __restrict__ out) {
    __shared__ ushort_t lh[16*392];      // 12544 B
    int blk = blockIdx.x;                // 1568
    int tid = threadIdx.x;
    int wv  = tid >> 6, lane = tid & 63;
    int quad = lane >> 4, nn = lane & 15;
    int p0  = blk * 16;
    int n   = p0 / HWHW;
    int hw0 = p0 % HWHW;

    const ushort_t* xrow = XLNt + (size_t)(p0 + nn)*96 + quad*8;
    bhalf8 a1[3];
    #pragma unroll
    for (int ks = 0; ks < 3; ++ks) a1[ks] = *(const bhalf8*)(xrow + ks*32);

    #pragma unroll 1
    for (int i = 0; i < 12; ++i) {
        int nt = wv*12 + i;
        floatx4 acc = (floatx4){0.f,0.f,0.f,0.f};
        #pragma unroll
        for (int ks = 0; ks < 3; ++ks) {
            bhalf8 bfr = *(const bhalf8*)(w1P + ((size_t)(nt*3 + ks)*64 + lane)*8);
            acc = __builtin_amdgcn_mfma_f32_16x16x32_bf16(a1[ks], bfr, acc, 0, 0, 0);
        }
        float b1v = b1[nt*16 + nn];
        #pragma unroll
        for (int r = 0; r < 4; ++r) {
            float h = acc[r] + b1v;
            h = 0.5f * h * (1.f + erff(h * 0.70710678118654752440f));
            lh[(quad*4 + r)*392 + nt*16 + nn] = bf1pack(h);
        }
    }
    __syncthreads();

    bhalf8 bf2[12];
    #pragma unroll
    for (int ks = 0; ks < 12; ++ks)
        bf2[ks] = *(const bhalf8*)&lh[nn*392 + ks*32 + quad*8];

    #pragma unroll 1
    for (int i = 0; i < 3; ++i) {
        int mt = wv*3 + i;
        floatx4 acc = (floatx4){0.f,0.f,0.f,0.f};
        #pragma unroll
        for (int ks = 0; ks < 12; ++ks) {
            bhalf8 af = *(const bhalf8*)(w2P + ((size_t)(mt*12 + ks)*64 + lane)*8);
            acc = __builtin_amdgcn_mfma_f32_16x16x32_bf16(af, bf2[ks], acc, 0, 0, 0);
        }
        #pragma unroll
        for (int r = 0; r < 4; ++r) {
            int c = mt*16 + quad*4 + r;
            size_t addr = ((size_t)n*CC_ + c)*HWHW + hw0 + nn;
            out[addr] += acc[r] + b2[c];
        }
    }
}

// ---------------------------------------------------------------------------
extern "C" void kernel_launch(void* const* d_in, const int* in_sizes, int n_in,
                              void* d_out, int out_size, void* d_ws, size_t ws_size,
                              hipStream_t stream) {
    const float* x    = (const float*)d_in[0];
    const float* ln1w = (const float*)d_in[1];
    const float* ln1b = (const float*)d_in[2];
    const float* wnn  = (const float*)d_in[3];
    const float* ln2w = (const float*)d_in[4];
    const float* ln2b = (const float*)d_in[5];
    const float* w1   = (const float*)d_in[6];
    const float* b1   = (const float*)d_in[7];
    const float* w2   = (const float*)d_in[8];
    const float* b2   = (const float*)d_in[9];
    float* out = (float*)d_out;
    char* ws = (char*)d_ws;

    float*    Wn   = (float*)ws;                      ws += 20736*4;
    ushort_t* WfP  = (ushort_t*)ws;                   ws += 73728*2;
    ushort_t* WtP  = (ushort_t*)ws;                   ws += 73728*2;
    ushort_t* w1P  = (ushort_t*)ws;                   ws += 36864*2;
    ushort_t* w2P  = (ushort_t*)ws;                   ws += 36864*2;
    unsigned* Xp   = (unsigned*)ws;                   ws += (size_t)(NELEM/2)*4;
    unsigned* Hu0  = (unsigned*)ws;                   ws += (size_t)(NELEM/2)*4;
    unsigned* Hu1  = (unsigned*)ws;                   ws += (size_t)(NELEM/2)*4;
    float*    SA   = (float*)ws;                      ws += (size_t)4*NPIX*4;
    float*    SB   = (float*)ws;                      ws += (size_t)4*NPIX*4;
    unsigned* XLNt = (unsigned*)ws;                   ws += (size_t)NPIX*48*4;

    // bf16(1/96) on host (RNE), and the matching per-group channel-sum init
    union { float f; unsigned u; } cv; cv.f = 1.f/96.f;
    unsigned ur = cv.u + 0x7fffu + ((cv.u >> 16) & 1u);
    unsigned short hbits = (unsigned short)(ur >> 16);
    unsigned huInit = ((unsigned)hbits << 16) | hbits;
    union { float f; unsigned u; } hv; hv.u = ((unsigned)hbits) << 16;
    float sInit = 24.f * hv.f;

    wnorm_n_kernel<<<CC_, 256, 0, stream>>>(wnn, Wn);
    wpack_kernel<<<144, 64, 0, stream>>>(Wn, WfP, WtP);
    mlppack_kernel<<<144, 64, 0, stream>>>(w1, w2, w1P, w2P);
    ln1_kernel<<<NPIX/256, 256, 0, stream>>>(x, ln1w, ln1b, Xp);
    fillu_kernel<<<(NELEM/2)/256, 256, 0, stream>>>(Hu0, NELEM/2, huInit);
    fill_kernel<<<(4*NPIX)/256, 256, 0, stream>>>(SA, 4*NPIX, sInit);

    for (int it = 0; it < NITER; ++it) {
        const unsigned* HuI  = (it & 1) ? Hu1 : Hu0;
        unsigned*       HuO  = (it & 1) ? Hu0 : Hu1;
        const float*    Scur = (it & 1) ? SB : SA;
        float*          Snxt = (it & 1) ? SA : SB;
        nnmf_mfma_kernel<<<896, 512, 0, stream>>>(HuI, HuO, Scur, Snxt, WtP, WfP, Xp);
    }
    // 25 iterations: final Hu in Hu1, final S in SB

    resln4_kernel<<<NPIX/256, 256, 0, stream>>>(x, Hu1, SB, ln2w, ln2b, out, XLNt);
    mlp5_kernel<<<NPIX/16, 128, 0, stream>>>((const ushort_t*)XLNt, w1P, b1, w2P, b2, out);
}